// Round 1
// baseline (1422.777 us; speedup 1.0000x reference)
//
#include <hip/hip_runtime.h>
#include <math.h>

// ---------------- problem constants ----------------
// B=2, IMG=512, FMC=1024, HID=512, A=9, NC=21, RED=16, POOL=7, TOP=20
// fm spatial: 32x32.  M1=2048 (b,i,j).  K(conv1)=768.  K(rpn)=9216. K(fc)=50176.

#define NEGV (-1e30f)

// output offsets (in floats)
#define O_RPN_REG 0
#define O_RPN_CLS 73728
#define O_NMS_REG 92160
#define O_NMS_CLS 92320
#define O_RCNN_REG 92360
#define O_RCNN_CLS 92520
#define O_ANCH 93360

// workspace offsets (in floats)
#define W_FM   0u            // 2*32*32*1024 = 2097152   (NHWC)
#define W_H    2097152u      // 2*32*32*512  = 1048576   (NHWC)
#define W_PROP 3145728u      // 2*9216*4     = 73728
#define W_SCR  3219456u      // 2*9216       = 18432
#define W_FLAT 3237888u      // 40*50176     = 2007040
#define W_HF   5244928u      // 40*1024      = 40960
#define W_WT   5285888u      // 512*9*1024   = 4718592   (optional)
#define WS_WT_END 10004480ull

static __device__ __forceinline__ float relu_(float v) { return fmaxf(v, 0.0f); }

// anchor half-extents, bit-matching numpy f64 -> f32
static __device__ __forceinline__ void anchor_wh(int a, float& w2, float& h2) {
    double s = (a < 3) ? 64.0 : (a < 6) ? 128.0 : 256.0;
    int rm = a - (a / 3) * 3;
    double r = (rm == 0) ? 0.5 : (rm == 1) ? 1.0 : 2.0;
    double sq = sqrt(r);
    w2 = (float)(s * sq) * 0.5f;   // wh[0]/2
    h2 = (float)(s / sq) * 0.5f;   // wh[1]/2
}

#define GEMM_INNER() do { \
  _Pragma("unroll") \
  for (int q8 = 0; q8 < 16; ++q8) { \
    const float4 a4 = *(const float4*)(&As[q8][ty * 4]); \
    const float4 b4 = *(const float4*)(&Bs2[q8][tx * 4]); \
    acc[0][0] += a4.x*b4.x; acc[0][1] += a4.x*b4.y; acc[0][2] += a4.x*b4.z; acc[0][3] += a4.x*b4.w; \
    acc[1][0] += a4.y*b4.x; acc[1][1] += a4.y*b4.y; acc[1][2] += a4.y*b4.z; acc[1][3] += a4.y*b4.w; \
    acc[2][0] += a4.z*b4.x; acc[2][1] += a4.z*b4.y; acc[2][2] += a4.z*b4.z; acc[2][3] += a4.z*b4.w; \
    acc[3][0] += a4.w*b4.x; acc[3][1] += a4.w*b4.y; acc[3][2] += a4.w*b4.z; acc[3][3] += a4.w*b4.w; \
  } \
} while (0)

// ---------------- conv1: stride-16 16x16 VALID conv == GEMM 2048x1024x768 ----------------
// A[m][k]: m=(b,i,j), k=c*256+y*16+x -> img[b,c,16i+y,16j+x]  (patches non-overlapping)
// B[n][k]: cnn_w flat (1024,768).  C -> fm NHWC [m][n], relu(+bias).
__global__ __launch_bounds__(256) void k_conv1(const float* __restrict__ img,
        const float* __restrict__ wgt, const float* __restrict__ bias,
        float* __restrict__ fm) {
    __shared__ __align__(16) float As[16][64];
    __shared__ __align__(16) float Bs2[16][64];
    const int tid = threadIdx.x;
    const int m0 = blockIdx.x * 64, n0 = blockIdx.y * 64;
    const int tx = tid & 15, ty = tid >> 4;
    const int lm = tid >> 2, lk4 = (tid & 3) * 4;
    const int am = m0 + lm;
    const int ab = am >> 10, ar = am & 1023, ai = ar >> 5, aj = ar & 31;
    const float* abase = img + (size_t)ab * (3 * 512 * 512) + (size_t)(ai * 16) * 512 + aj * 16;
    const float* bbase = wgt + (size_t)(n0 + lm) * 768;
    float acc[4][4] = {{0.f}};
    for (int c = 0; c < 3; ++c) {
        for (int y = 0; y < 16; ++y) {
            const float4 av = *(const float4*)(abase + (size_t)c * (512 * 512) + y * 512 + lk4);
            const float4 bv = *(const float4*)(bbase + c * 256 + y * 16 + lk4);
            As[lk4 + 0][lm] = av.x; As[lk4 + 1][lm] = av.y; As[lk4 + 2][lm] = av.z; As[lk4 + 3][lm] = av.w;
            Bs2[lk4 + 0][lm] = bv.x; Bs2[lk4 + 1][lm] = bv.y; Bs2[lk4 + 2][lm] = bv.z; Bs2[lk4 + 3][lm] = bv.w;
            __syncthreads();
            GEMM_INNER();
            __syncthreads();
        }
    }
#pragma unroll
    for (int rr = 0; rr < 4; ++rr) {
        const int m = m0 + ty * 4 + rr;
        const int n = n0 + tx * 4;
        float4 o;
        o.x = relu_(acc[rr][0] + bias[n + 0]);
        o.y = relu_(acc[rr][1] + bias[n + 1]);
        o.z = relu_(acc[rr][2] + bias[n + 2]);
        o.w = relu_(acc[rr][3] + bias[n + 3]);
        *(float4*)(fm + (size_t)m * 1024 + n) = o;
    }
}

// ---------------- rpn weight transpose: (512,1024,3,3) -> wt[oc][d][ic] ----------------
__global__ void k_wt(const float* __restrict__ w, float* __restrict__ wt) {
    const int o = blockIdx.x * 256 + threadIdx.x;
    if (o >= 512 * 9216) return;
    const int ic = o & 1023;
    const int t1 = o >> 10;        // oc*9 + d
    const int d = t1 % 9;
    const int oc = t1 / 9;
    wt[o] = w[(size_t)oc * 9216 + (size_t)ic * 9 + d];
}

// ---------------- rpn 3x3 SAME conv == GEMM 2048x512x9216, k-order (d, ic) ----------------
__global__ __launch_bounds__(256) void k_rpn(const float* __restrict__ fm,
        const float* __restrict__ wgt, const float* __restrict__ wt,
        const float* __restrict__ bias, float* __restrict__ hout, const int use_wt) {
    __shared__ __align__(16) float As[16][64];
    __shared__ __align__(16) float Bs2[16][64];
    const int tid = threadIdx.x;
    const int m0 = blockIdx.x * 64, n0 = blockIdx.y * 64;
    const int tx = tid & 15, ty = tid >> 4;
    const int lm = tid >> 2, lk4 = (tid & 3) * 4;
    const int am = m0 + lm;
    const int ab = am >> 10, ai = (am >> 5) & 31, aj = am & 31;
    const float* wrow = wgt + (size_t)(n0 + lm) * 9216;
    const float* wtrow = wt + (size_t)(n0 + lm) * 9216;
    float acc[4][4] = {{0.f}};
    for (int d = 0; d < 9; ++d) {
        const int di = d / 3, dj = d - di * 3;
        const int y = ai + di - 1, x = aj + dj - 1;
        const bool aok = ((unsigned)y < 32u) && ((unsigned)x < 32u);
        const int yc = aok ? y : 0, xc = aok ? x : 0;
        const float* arow = fm + (((size_t)(ab * 32 + yc)) * 32 + xc) * 1024;
        for (int icb = 0; icb < 1024; icb += 16) {
            float4 av = make_float4(0.f, 0.f, 0.f, 0.f);
            if (aok) av = *(const float4*)(arow + icb + lk4);
            float4 bv;
            if (use_wt) {
                bv = *(const float4*)(wtrow + d * 1024 + icb + lk4);
            } else {
                const float* p = wrow + (size_t)(icb + lk4) * 9 + d;
                bv.x = p[0]; bv.y = p[9]; bv.z = p[18]; bv.w = p[27];
            }
            As[lk4 + 0][lm] = av.x; As[lk4 + 1][lm] = av.y; As[lk4 + 2][lm] = av.z; As[lk4 + 3][lm] = av.w;
            Bs2[lk4 + 0][lm] = bv.x; Bs2[lk4 + 1][lm] = bv.y; Bs2[lk4 + 2][lm] = bv.z; Bs2[lk4 + 3][lm] = bv.w;
            __syncthreads();
            GEMM_INNER();
            __syncthreads();
        }
    }
#pragma unroll
    for (int rr = 0; rr < 4; ++rr) {
        const int m = m0 + ty * 4 + rr;
        const int n = n0 + tx * 4;
        float4 o;
        o.x = relu_(acc[rr][0] + bias[n + 0]);
        o.y = relu_(acc[rr][1] + bias[n + 1]);
        o.z = relu_(acc[rr][2] + bias[n + 2]);
        o.w = relu_(acc[rr][3] + bias[n + 3]);
        *(float4*)(hout + (size_t)m * 512 + n) = o;
    }
}

// ---------------- rpn heads (1x1 convs) + anchors + proposals ----------------
__global__ __launch_bounds__(64) void k_rpn_heads(const float* __restrict__ h,
        const float* __restrict__ regw, const float* __restrict__ regb,
        const float* __restrict__ clsw, const float* __restrict__ clsb,
        float* __restrict__ out, float* __restrict__ prop, float* __restrict__ scr) {
    __shared__ __align__(16) float hrow[512];
    const int m = blockIdx.x, tid = threadIdx.x;
    const int b = m >> 10, q = m & 1023, ii = q >> 5, jj = q & 31;
    for (int i = tid * 4; i < 512; i += 256)
        *(float4*)&hrow[i] = *(const float4*)(h + (size_t)m * 512 + i);
    __syncthreads();
    if (tid < 45) {
        const int isreg = (tid < 36);
        const float* wp = isreg ? (regw + (size_t)tid * 512) : (clsw + (size_t)(tid - 36) * 512);
        float acc2 = isreg ? regb[tid] : clsb[tid - 36];
        for (int k = 0; k < 512; k += 4) {
            const float4 wv = *(const float4*)(wp + k);
            acc2 += hrow[k + 0] * wv.x; acc2 += hrow[k + 1] * wv.y;
            acc2 += hrow[k + 2] * wv.z; acc2 += hrow[k + 3] * wv.w;
        }
        if (isreg) {
            out[O_RPN_REG + (size_t)b * 36864 + q * 36 + tid] = acc2;
            const int a = tid >> 2, cc = tid & 3;
            float w2, h2; anchor_wh(a, w2, h2);
            const float cx = ((float)jj + 0.5f) * 16.f, cy = ((float)ii + 0.5f) * 16.f;
            const float av = (cc == 0) ? cx - w2 : (cc == 1) ? cy - h2 : (cc == 2) ? cx + w2 : cy + h2;
            prop[(size_t)b * 36864 + q * 36 + tid] = acc2 + av;
        } else {
            const int n = tid - 36;
            out[O_RPN_CLS + (size_t)b * 9216 + q * 9 + n] = acc2;
            scr[(size_t)b * 9216 + q * 9 + n] = acc2;
        }
    }
    if (b == 0 && tid >= 48 && tid < 57) {
        const int a = tid - 48;
        float w2, h2; anchor_wh(a, w2, h2);
        const float cx = ((float)jj + 0.5f) * 16.f, cy = ((float)ii + 0.5f) * 16.f;
        const float4 av4 = make_float4(cx - w2, cy - h2, cx + w2, cy + h2);
        *(float4*)(out + O_ANCH + (size_t)(q * 9 + a) * 4) = av4;
    }
}

// ---------------- NMS: one block per batch, scores in LDS, 20 serial selections ----------------
__global__ __launch_bounds__(256) void k_nms(const float* __restrict__ prop,
        const float* __restrict__ scr, float* __restrict__ out) {
    __shared__ float sv[9216];
    __shared__ float rv[256];
    __shared__ int ri[256];
    __shared__ float bxs[4];
    __shared__ int seli;
    const int b = blockIdx.x, tid = threadIdx.x;
    const float* P = prop + (size_t)b * 36864;
    for (int i = tid; i < 9216; i += 256) sv[i] = scr[b * 9216 + i];
    __syncthreads();
    for (int t = 0; t < 20; ++t) {
        float bv = -3.4e38f; int bi = 0;
        for (int i = tid; i < 9216; i += 256) {
            const float v = sv[i];
            if (v > bv) { bv = v; bi = i; }   // ascending i per thread -> first-max kept
        }
        rv[tid] = bv; ri[tid] = bi;
        __syncthreads();
        for (int off = 128; off > 0; off >>= 1) {
            if (tid < off) {
                const float v2 = rv[tid + off]; const int i2 = ri[tid + off];
                if (v2 > rv[tid] || (v2 == rv[tid] && i2 < ri[tid])) { rv[tid] = v2; ri[tid] = i2; }
            }
            __syncthreads();
        }
        if (tid == 0) {
            const int i = ri[0]; seli = i;
            const float4 bb = *(const float4*)(P + (size_t)i * 4);
            bxs[0] = bb.x; bxs[1] = bb.y; bxs[2] = bb.z; bxs[3] = bb.w;
            *(float4*)(out + O_NMS_REG + (size_t)(b * 20 + t) * 4) = bb;
            out[O_NMS_CLS + b * 20 + t] = rv[0];
        }
        __syncthreads();
        const float bx0 = bxs[0], by0 = bxs[1], bx1 = bxs[2], by1 = bxs[3];
        const float ab2 = fmaxf(bx1 - bx0, 0.f) * fmaxf(by1 - by0, 0.f);
        const int si = seli;
        for (int i = tid; i < 9216; i += 256) {
            const float4 qb = *(const float4*)(P + (size_t)i * 4);
            const float ix1 = fmaxf(bx0, qb.x), iy1 = fmaxf(by0, qb.y);
            const float ix2 = fminf(bx1, qb.z), iy2 = fminf(by1, qb.w);
            const float inter = fmaxf(ix2 - ix1, 0.f) * fmaxf(iy2 - iy1, 0.f);
            const float ar2 = fmaxf(qb.z - qb.x, 0.f) * fmaxf(qb.w - qb.y, 0.f);
            const float iou = inter / (ab2 + ar2 - inter + 1e-8f);
            if (iou > 0.3f || i == si) sv[i] = NEGV;
        }
        __syncthreads();
    }
}

// ---------------- ROI align -> flat [40][50176], col = c*49 + py*7 + px ----------------
__global__ __launch_bounds__(256) void k_roi(const float* __restrict__ fm,
        const int* __restrict__ img_id, const float* __restrict__ nreg,
        float* __restrict__ flat) {
    const int py = blockIdx.x, roi = blockIdx.y, b = blockIdx.z;
    const float* bx = nreg + (size_t)(b * 20 + roi) * 4;
    const float b0 = bx[0] * 0.0625f, b1 = bx[1] * 0.0625f;
    const float b2 = bx[2] * 0.0625f, b3 = bx[3] * 0.0625f;
    const float wd = fmaxf(b2 - b0, 0.f), hg = fmaxf(b3 - b1, 0.f);
    const float tyv = ((float)py + 0.5f) / 7.0f;
    const float ycv = fminf(fmaxf(b1 + hg * tyv, 0.f), 31.f);
    const float y0f = floorf(ycv);
    const int y0 = (int)y0f, y1 = min(y0 + 1, 31);
    const float ly = ycv - y0f, omly = 1.f - ly;
    const int bb = img_id[b];
    const float* fmb = fm + (size_t)bb * (32 * 32 * 1024);
    const size_t orow = (size_t)(b * 20 + roi) * 50176 + (size_t)py * 7;
    for (int px = 0; px < 7; ++px) {
        const float txv = ((float)px + 0.5f) / 7.0f;
        const float xcv = fminf(fmaxf(b0 + wd * txv, 0.f), 31.f);
        const float x0f = floorf(xcv);
        const int x0 = (int)x0f, x1 = min(x0 + 1, 31);
        const float lx = xcv - x0f, omlx = 1.f - lx;
        const int o00 = ((y0 * 32) + x0) << 10, o01 = ((y0 * 32) + x1) << 10;
        const int o10 = ((y1 * 32) + x0) << 10, o11 = ((y1 * 32) + x1) << 10;
        for (int u = 0; u < 4; ++u) {
            const int c = threadIdx.x + u * 256;
            const float v00 = fmb[o00 + c], v01 = fmb[o01 + c];
            const float v10 = fmb[o10 + c], v11 = fmb[o11 + c];
            const float val = ((v00 * omly) * omlx) + ((v01 * omly) * lx)
                            + ((v10 * ly) * omlx) + ((v11 * ly) * lx);
            flat[orow + (size_t)c * 49 + px] = val;
        }
    }
}

// ---------------- hf accumulator init (bias) ----------------
__global__ void k_hf_init(const float* __restrict__ fcb, float* __restrict__ hf) {
    const int i = blockIdx.x * 256 + threadIdx.x;
    if (i < 40 * 1024) hf[i] = fcb[i & 1023];
}

// ---------------- FC GEMM: (40 pad 64) x 1024 x 50176, split-K=49, atomic accumulate ----------------
__global__ __launch_bounds__(256) void k_fc(const float* __restrict__ flat,
        const float* __restrict__ fcw, float* __restrict__ hf) {
    __shared__ __align__(16) float As[16][64];
    __shared__ __align__(16) float Bs2[16][64];
    const int tid = threadIdx.x;
    const int n0 = blockIdx.x * 64;
    const int kb = blockIdx.y * 1024;
    const int tx = tid & 15, ty = tid >> 4;
    const int lm = tid >> 2, lk4 = (tid & 3) * 4;
    const int lkb = tid >> 4, ln4 = (tid & 15) * 4;
    const float* arow = flat + (size_t)lm * 50176 + kb;
    float acc[4][4] = {{0.f}};
    for (int kq = 0; kq < 1024; kq += 16) {
        float4 av = make_float4(0.f, 0.f, 0.f, 0.f);
        if (lm < 40) av = *(const float4*)(arow + kq + lk4);
        const float4 bv = *(const float4*)(fcw + (size_t)(kb + kq + lkb) * 1024 + n0 + ln4);
        As[lk4 + 0][lm] = av.x; As[lk4 + 1][lm] = av.y; As[lk4 + 2][lm] = av.z; As[lk4 + 3][lm] = av.w;
        *(float4*)&Bs2[lkb][ln4] = bv;
        __syncthreads();
        GEMM_INNER();
        __syncthreads();
    }
#pragma unroll
    for (int rr = 0; rr < 4; ++rr) {
        const int m = ty * 4 + rr;
        if (m < 40) {
#pragma unroll
            for (int ss = 0; ss < 4; ++ss)
                atomicAdd(hf + (size_t)m * 1024 + n0 + tx * 4 + ss, acc[rr][ss]);
        }
    }
}

// ---------------- final heads: rcnn_reg, rcnn_cls ----------------
__global__ __launch_bounds__(64) void k_heads(const float* __restrict__ hf,
        const float* __restrict__ regw, const float* __restrict__ regb,
        const float* __restrict__ clsw, const float* __restrict__ clsb,
        float* __restrict__ out) {
    __shared__ __align__(16) float hrow[1024];
    const int m = blockIdx.x, tid = threadIdx.x;
    for (int i = tid * 4; i < 1024; i += 256) {
        const float4 v = *(const float4*)(hf + (size_t)m * 1024 + i);
        hrow[i + 0] = relu_(v.x); hrow[i + 1] = relu_(v.y);
        hrow[i + 2] = relu_(v.z); hrow[i + 3] = relu_(v.w);
    }
    __syncthreads();
    if (tid < 25) {
        float acc2 = 0.f;
        if (tid < 4) {
            for (int k = 0; k < 1024; ++k) acc2 += hrow[k] * regw[(size_t)k * 4 + tid];
            out[O_RCNN_REG + m * 4 + tid] = acc2 + regb[tid];
        } else {
            const int n = tid - 4;
            for (int k = 0; k < 1024; ++k) acc2 += hrow[k] * clsw[(size_t)k * 21 + n];
            out[O_RCNN_CLS + m * 21 + n] = acc2 + clsb[n];
        }
    }
}

extern "C" void kernel_launch(void* const* d_in, const int* in_sizes, int n_in,
                              void* d_out, int out_size, void* d_ws, size_t ws_size,
                              hipStream_t stream) {
    (void)in_sizes; (void)n_in; (void)out_size;
    const float* img       = (const float*)d_in[0];
    const int*   img_id    = (const int*)  d_in[1];
    const float* cnn_w     = (const float*)d_in[2];
    const float* cnn_b     = (const float*)d_in[3];
    const float* rpn_w     = (const float*)d_in[4];
    const float* rpn_b     = (const float*)d_in[5];
    const float* rpn_reg_w = (const float*)d_in[6];
    const float* rpn_reg_b = (const float*)d_in[7];
    const float* rpn_cls_w = (const float*)d_in[8];
    const float* rpn_cls_b = (const float*)d_in[9];
    const float* fc_w      = (const float*)d_in[10];
    const float* fc_b      = (const float*)d_in[11];
    const float* reg_w     = (const float*)d_in[12];
    const float* reg_b     = (const float*)d_in[13];
    const float* cls_w     = (const float*)d_in[14];
    const float* cls_b     = (const float*)d_in[15];
    float* out = (float*)d_out;
    float* ws  = (float*)d_ws;

    float* fm   = ws + W_FM;
    float* hbuf = ws + W_H;
    float* prop = ws + W_PROP;
    float* scr  = ws + W_SCR;
    float* flat = ws + W_FLAT;
    float* hf   = ws + W_HF;
    float* wt   = ws + W_WT;
    const int use_wt = (ws_size >= WS_WT_END * 4ull) ? 1 : 0;

    if (use_wt) k_wt<<<(512 * 9216 + 255) / 256, 256, 0, stream>>>(rpn_w, wt);
    k_conv1<<<dim3(32, 16), 256, 0, stream>>>(img, cnn_w, cnn_b, fm);
    k_rpn<<<dim3(32, 8), 256, 0, stream>>>(fm, rpn_w, wt, rpn_b, hbuf, use_wt);
    k_rpn_heads<<<2048, 64, 0, stream>>>(hbuf, rpn_reg_w, rpn_reg_b, rpn_cls_w, rpn_cls_b,
                                         out, prop, scr);
    k_nms<<<2, 256, 0, stream>>>(prop, scr, out);
    k_roi<<<dim3(7, 20, 2), 256, 0, stream>>>(fm, img_id, out + O_NMS_REG, flat);
    k_hf_init<<<(40 * 1024 + 255) / 256, 256, 0, stream>>>(fc_b, hf);
    k_fc<<<dim3(16, 49), 256, 0, stream>>>(flat, fc_w, hf);
    k_heads<<<40, 64, 0, stream>>>(hf, reg_w, reg_b, cls_w, cls_b, out);
}

// Round 2
// 823.729 us; speedup vs baseline: 1.7272x; 1.7272x over previous
//
#include <hip/hip_runtime.h>
#include <math.h>

// ---------------- problem constants ----------------
// B=2, IMG=512, FMC=1024, HID=512, A=9, NC=21, RED=16, POOL=7, TOP=20
// fm spatial 32x32. GEMMs: conv1 2048x1024x768, rpn 2048x512x9216, fc 40x1024x50176.

#define NEGV (-1e30f)

typedef unsigned short u16;
typedef float v4f __attribute__((ext_vector_type(4)));
typedef short short8 __attribute__((ext_vector_type(8)));

// output offsets (floats)
#define O_RPN_REG 0
#define O_RPN_CLS 73728
#define O_NMS_REG 92160
#define O_NMS_CLS 92320
#define O_RCNN_REG 92360
#define O_RCNN_CLS 92520
#define O_ANCH 93360

// workspace offsets (floats)
#define W_FM   0u            // 2048*1024 fm NHWC fp32
#define W_H    2097152u      // 2048*512 h fp32
#define W_PROP 3145728u      // 2*9216*4
#define W_SCR  3219456u      // 2*9216
#define W_FLAT 3237888u      // 40*50176
#define W_HF   5244928u      // 40*1024
#define W_A1H  5285888u      // 2048*768 u16 -> 786432 floats
#define W_A1L  6072320u
#define W_B1H  6858752u      // 1024*768 u16 -> 393216 floats
#define W_B1L  7251968u
#define W_FMH  7645184u      // 2048*1024 u16 -> 1048576 floats
#define W_FML  8693760u
#define W_B2H  9742336u      // 512*9216 u16 -> 2359296 floats
#define W_B2L  12101632u
#define W_PART 14460928u     // 2 * 2048*512 fp32
// end = 16,558,080 floats = 66.2 MB

static __device__ __forceinline__ float relu_(float v) { return fmaxf(v, 0.0f); }

// fp32 -> bf16 hi/lo split (RTNE)
static __device__ __forceinline__ u16 bf16_rtne(float x) {
    unsigned int u = __float_as_uint(x);
    unsigned int r = u + 0x7fffu + ((u >> 16) & 1u);
    return (u16)(r >> 16);
}
static __device__ __forceinline__ void split2(float x, u16& h, u16& l) {
    h = bf16_rtne(x);
    const float hf = __uint_as_float(((unsigned int)h) << 16);
    l = bf16_rtne(x - hf);
}

// anchor half-extents, bit-matching numpy f64 -> f32
static __device__ __forceinline__ void anchor_wh(int a, float& w2, float& h2) {
    double s = (a < 3) ? 64.0 : (a < 6) ? 128.0 : 256.0;
    int rm = a - (a / 3) * 3;
    double r = (rm == 0) ? 0.5 : (rm == 1) ? 1.0 : 2.0;
    double sq = sqrt(r);
    w2 = (float)(s * sq) * 0.5f;
    h2 = (float)(s / sq) * 0.5f;
}

// ---------------- prep: conv1 im2col A (bf16 hi/lo) ----------------
// A1[m][k], m=(b,i,j), k=c*256+y*16+x -> img[b,c,16i+y,16j+x]
__global__ void k_prep_a1(const float* __restrict__ img, u16* __restrict__ a1h, u16* __restrict__ a1l) {
    const int idx = blockIdx.x * 256 + threadIdx.x;        // 393216
    const int m = idx / 192, kq = (idx - m * 192) * 4;
    const int b = m >> 10, i = (m >> 5) & 31, j = m & 31;
    const int c = kq >> 8, rem = kq & 255, y = rem >> 4, x = rem & 15;
    const float4 v = *(const float4*)(img + ((size_t)((b * 3 + c) * 512 + i * 16 + y)) * 512 + j * 16 + x);
    ushort4 H, Lo;
    split2(v.x, H.x, Lo.x); split2(v.y, H.y, Lo.y);
    split2(v.z, H.z, Lo.z); split2(v.w, H.w, Lo.w);
    *(ushort4*)(a1h + (size_t)idx * 4) = H;
    *(ushort4*)(a1l + (size_t)idx * 4) = Lo;
}

// ---------------- prep: generic elementwise fp32 -> bf16 hi/lo ----------------
__global__ void k_split4(const float* __restrict__ src, u16* __restrict__ h, u16* __restrict__ l, int n4) {
    const int idx = blockIdx.x * 256 + threadIdx.x;
    if (idx >= n4) return;
    const float4 v = *(const float4*)(src + (size_t)idx * 4);
    ushort4 H, Lo;
    split2(v.x, H.x, Lo.x); split2(v.y, H.y, Lo.y);
    split2(v.z, H.z, Lo.z); split2(v.w, H.w, Lo.w);
    *(ushort4*)(h + (size_t)idx * 4) = H;
    *(ushort4*)(l + (size_t)idx * 4) = Lo;
}

// ---------------- prep: rpn weights (512,1024,3,3) -> B2[oc][d*1024+ic] bf16 hi/lo ----------------
__global__ void k_prep_w2(const float* __restrict__ w, u16* __restrict__ bh, u16* __restrict__ bl) {
    const int idx = blockIdx.x * 256 + threadIdx.x;        // 1,179,648
    const int oc = idx / 2304, r = idx - oc * 2304, d = r >> 8, ic4 = (r & 255) * 4;
    const float* p = w + (size_t)oc * 9216 + (size_t)ic4 * 9 + d;
    float4 v; v.x = p[0]; v.y = p[9]; v.z = p[18]; v.w = p[27];
    ushort4 H, Lo;
    split2(v.x, H.x, Lo.x); split2(v.y, H.y, Lo.y);
    split2(v.z, H.z, Lo.z); split2(v.w, H.w, Lo.w);
    const size_t o = (size_t)oc * 9216 + d * 1024 + ic4;
    *(ushort4*)(bh + o) = H;
    *(ushort4*)(bl + o) = Lo;
}

// ---------------- MFMA bf16x3 GEMM ----------------
// C[M][ldc] (+bias,relu optional) = A[M][K] * B[N][K]^T, A/B given as bf16 hi/lo.
// Block tile 128(M) x 64(N), 256 thr = 4 waves, wave tile 64x32 (mt=4, nt=2), K-chunk 32.
// MODE 0: A linear rows (row length KA). MODE 1: rpn gather - A rows are d-shifted fm
//   rows (fmh/fml [2048][1024] bf16), chunk c -> d=c>>4, ic=icoff+(c&15)*32; split-K via
//   blockIdx.z (icoff = z*512), C += z*2048*512.
// MFMA 16x16x32_bf16: A-frag A[m=lane&15][k=(lane>>4)*8+j]; B-frag Bt[n=lane&15][k=..];
// C/D: col=lane&15, row=(lane>>4)*4+reg  (m89-verified mapping).
template<int MODE>
__global__ __launch_bounds__(256, 1) void k_gemm(
        const u16* __restrict__ Agh, const u16* __restrict__ Agl,
        const u16* __restrict__ Bgh, const u16* __restrict__ Bgl,
        const float* __restrict__ bias, float* __restrict__ Cout,
        const int KA, const int KB, const int nchunk, const int ldc, const int do_bias_relu) {
    __shared__ __align__(16) u16 AsH[128 * 32];
    __shared__ __align__(16) u16 AsL[128 * 32];
    __shared__ __align__(16) u16 BsH[64 * 32];
    __shared__ __align__(16) u16 BsL[64 * 32];
    const int tid = threadIdx.x;
    const int w = tid >> 6, L = tid & 63;
    const int q = L >> 4, lr = L & 15;
    const int wm = w >> 1, wn = w & 1;
    const int m0 = blockIdx.x * 128, n0 = blockIdx.y * 64;
    const int icoff = blockIdx.z * 512;
    float* C = Cout + (MODE == 1 ? (size_t)blockIdx.z * (2048u * 512u) : (size_t)0);
    const int seg = L & 3, rsub = L >> 2;

    // staging slots: 24 insts of 16 rows x 64B; wave w handles idx w*6..w*6+5
    u16* ldst[6];
    const u16* gbase[6];
    int arow_b[6], arow_i[6], arow_j[6];
    int kindv[6];
#pragma unroll
    for (int s = 0; s < 6; ++s) {
        const int idx = w * 6 + s;
        int kind, inst;
        if (idx < 8)       { kind = 0; inst = idx; }
        else if (idx < 16) { kind = 1; inst = idx - 8; }
        else if (idx < 20) { kind = 2; inst = idx - 16; }
        else               { kind = 3; inst = idx - 20; }
        kindv[s] = kind;
        const int r = inst * 16 + rsub;
        u16* lb = (kind == 0) ? AsH : (kind == 1) ? AsL : (kind == 2) ? BsH : BsL;
        ldst[s] = lb + r * 32 + seg * 8;
        arow_b[s] = 0; arow_i[s] = 0; arow_j[s] = 0;
        if (kind >= 2) {
            const u16* gb = (kind == 2) ? Bgh : Bgl;
            gbase[s] = gb + (size_t)(n0 + r) * KB + seg * 8;
        } else if (MODE == 0) {
            const u16* gb = (kind == 0) ? Agh : Agl;
            gbase[s] = gb + (size_t)(m0 + r) * KA + seg * 8;
        } else {
            const int m = m0 + r;
            arow_b[s] = m >> 10; arow_i[s] = (m >> 5) & 31; arow_j[s] = m & 31;
            gbase[s] = (kind == 0) ? Agh : Agl;
        }
    }

    v4f acc[4][2];
#pragma unroll
    for (int t = 0; t < 4; ++t)
#pragma unroll
        for (int u2 = 0; u2 < 2; ++u2) acc[t][u2] = (v4f){0.f, 0.f, 0.f, 0.f};

    uint4 ubuf[6];
    bool okbuf[6];

#define LOAD6(c_) do { \
    int d_, ic_, kB_; \
    if (MODE == 0) { kB_ = (c_) * 32; d_ = 0; ic_ = kB_; } \
    else { d_ = (c_) >> 4; ic_ = icoff + ((c_) & 15) * 32; kB_ = d_ * 1024 + ic_; } \
    const int di_ = d_ / 3, dj_ = d_ - di_ * 3; \
    _Pragma("unroll") \
    for (int s = 0; s < 6; ++s) { \
        if (kindv[s] >= 2) { ubuf[s] = *(const uint4*)(gbase[s] + kB_); okbuf[s] = true; } \
        else if (MODE == 0) { ubuf[s] = *(const uint4*)(gbase[s] + ic_); okbuf[s] = true; } \
        else { \
            const int y_ = arow_i[s] + di_ - 1, x_ = arow_j[s] + dj_ - 1; \
            const bool ok_ = ((unsigned)y_ < 32u) && ((unsigned)x_ < 32u); \
            const int yc_ = ok_ ? y_ : 0, xc_ = ok_ ? x_ : 0; \
            ubuf[s] = *(const uint4*)(gbase[s] + (size_t)(((arow_b[s] * 32 + yc_) * 32 + xc_)) * 1024 + ic_ + seg * 8); \
            okbuf[s] = ok_; \
        } \
    } \
} while (0)

    LOAD6(0);
    for (int c = 0; c < nchunk; ++c) {
        __syncthreads();
#pragma unroll
        for (int s = 0; s < 6; ++s) {
            uint4 v = ubuf[s];
            if (MODE == 1 && !okbuf[s]) { v.x = 0u; v.y = 0u; v.z = 0u; v.w = 0u; }
            *(uint4*)ldst[s] = v;
        }
        __syncthreads();
        if (c + 1 < nchunk) LOAD6(c + 1);
        short8 ah[4], al[4], bh[2], bl[2];
#pragma unroll
        for (int t = 0; t < 4; ++t) {
            ah[t] = *(const short8*)(AsH + (wm * 64 + t * 16 + lr) * 32 + q * 8);
            al[t] = *(const short8*)(AsL + (wm * 64 + t * 16 + lr) * 32 + q * 8);
        }
#pragma unroll
        for (int u2 = 0; u2 < 2; ++u2) {
            bh[u2] = *(const short8*)(BsH + (wn * 32 + u2 * 16 + lr) * 32 + q * 8);
            bl[u2] = *(const short8*)(BsL + (wn * 32 + u2 * 16 + lr) * 32 + q * 8);
        }
#pragma unroll
        for (int t = 0; t < 4; ++t)
#pragma unroll
            for (int u2 = 0; u2 < 2; ++u2) {
                acc[t][u2] = __builtin_amdgcn_mfma_f32_16x16x32_bf16(ah[t], bh[u2], acc[t][u2], 0, 0, 0);
                acc[t][u2] = __builtin_amdgcn_mfma_f32_16x16x32_bf16(ah[t], bl[u2], acc[t][u2], 0, 0, 0);
                acc[t][u2] = __builtin_amdgcn_mfma_f32_16x16x32_bf16(al[t], bh[u2], acc[t][u2], 0, 0, 0);
            }
    }
#undef LOAD6

#pragma unroll
    for (int t = 0; t < 4; ++t) {
        const int row = m0 + wm * 64 + t * 16 + q * 4;
#pragma unroll
        for (int u2 = 0; u2 < 2; ++u2) {
            const int col = n0 + wn * 32 + u2 * 16 + lr;
            const float bv = do_bias_relu ? bias[col] : 0.f;
#pragma unroll
            for (int r = 0; r < 4; ++r) {
                float vv = acc[t][u2][r];
                if (do_bias_relu) vv = relu_(vv + bv);
                C[(size_t)(row + r) * ldc + col] = vv;
            }
        }
    }
}

// ---------------- reduce rpn split-K partials + bias + relu -> h ----------------
__global__ void k_reduce(const float* __restrict__ part, const float* __restrict__ bias,
                         float* __restrict__ h) {
    const int i4 = (blockIdx.x * 256 + threadIdx.x) * 4;
    const float4 a = *(const float4*)(part + i4);
    const float4 b = *(const float4*)(part + 2048 * 512 + i4);
    const int n = i4 & 511;
    const float4 bv = *(const float4*)(bias + n);
    float4 o;
    o.x = relu_(a.x + b.x + bv.x); o.y = relu_(a.y + b.y + bv.y);
    o.z = relu_(a.z + b.z + bv.z); o.w = relu_(a.w + b.w + bv.w);
    *(float4*)(h + i4) = o;
}

// ---------------- rpn heads (1x1 convs) + anchors + proposals ----------------
__global__ __launch_bounds__(64) void k_rpn_heads(const float* __restrict__ h,
        const float* __restrict__ regw, const float* __restrict__ regb,
        const float* __restrict__ clsw, const float* __restrict__ clsb,
        float* __restrict__ out, float* __restrict__ prop, float* __restrict__ scr) {
    __shared__ __align__(16) float hrow[512];
    const int m = blockIdx.x, tid = threadIdx.x;
    const int b = m >> 10, qd = m & 1023, ii = qd >> 5, jj = qd & 31;
    for (int i = tid * 4; i < 512; i += 256)
        *(float4*)&hrow[i] = *(const float4*)(h + (size_t)m * 512 + i);
    __syncthreads();
    if (tid < 45) {
        const int isreg = (tid < 36);
        const float* wp = isreg ? (regw + (size_t)tid * 512) : (clsw + (size_t)(tid - 36) * 512);
        float acc2 = isreg ? regb[tid] : clsb[tid - 36];
        for (int k = 0; k < 512; k += 4) {
            const float4 wv = *(const float4*)(wp + k);
            acc2 += hrow[k + 0] * wv.x; acc2 += hrow[k + 1] * wv.y;
            acc2 += hrow[k + 2] * wv.z; acc2 += hrow[k + 3] * wv.w;
        }
        if (isreg) {
            out[O_RPN_REG + (size_t)b * 36864 + qd * 36 + tid] = acc2;
            const int a = tid >> 2, cc = tid & 3;
            float w2, h2; anchor_wh(a, w2, h2);
            const float cx = ((float)jj + 0.5f) * 16.f, cy = ((float)ii + 0.5f) * 16.f;
            const float av = (cc == 0) ? cx - w2 : (cc == 1) ? cy - h2 : (cc == 2) ? cx + w2 : cy + h2;
            prop[(size_t)b * 36864 + qd * 36 + tid] = acc2 + av;
        } else {
            const int n = tid - 36;
            out[O_RPN_CLS + (size_t)b * 9216 + qd * 9 + n] = acc2;
            scr[(size_t)b * 9216 + qd * 9 + n] = acc2;
        }
    }
    if (b == 0 && tid >= 48 && tid < 57) {
        const int a = tid - 48;
        float w2, h2; anchor_wh(a, w2, h2);
        const float cx = ((float)jj + 0.5f) * 16.f, cy = ((float)ii + 0.5f) * 16.f;
        const float4 av4 = make_float4(cx - w2, cy - h2, cx + w2, cy + h2);
        *(float4*)(out + O_ANCH + (size_t)(qd * 9 + a) * 4) = av4;
    }
}

// ---------------- NMS ----------------
__global__ __launch_bounds__(256) void k_nms(const float* __restrict__ prop,
        const float* __restrict__ scr, float* __restrict__ out) {
    __shared__ float sv[9216];
    __shared__ float rv[256];
    __shared__ int ri[256];
    __shared__ float bxs[4];
    __shared__ int seli;
    const int b = blockIdx.x, tid = threadIdx.x;
    const float* P = prop + (size_t)b * 36864;
    for (int i = tid; i < 9216; i += 256) sv[i] = scr[b * 9216 + i];
    __syncthreads();
    for (int t = 0; t < 20; ++t) {
        float bv = -3.4e38f; int bi = 0;
        for (int i = tid; i < 9216; i += 256) {
            const float v = sv[i];
            if (v > bv) { bv = v; bi = i; }
        }
        rv[tid] = bv; ri[tid] = bi;
        __syncthreads();
        for (int off = 128; off > 0; off >>= 1) {
            if (tid < off) {
                const float v2 = rv[tid + off]; const int i2 = ri[tid + off];
                if (v2 > rv[tid] || (v2 == rv[tid] && i2 < ri[tid])) { rv[tid] = v2; ri[tid] = i2; }
            }
            __syncthreads();
        }
        if (tid == 0) {
            const int i = ri[0]; seli = i;
            const float4 bb = *(const float4*)(P + (size_t)i * 4);
            bxs[0] = bb.x; bxs[1] = bb.y; bxs[2] = bb.z; bxs[3] = bb.w;
            *(float4*)(out + O_NMS_REG + (size_t)(b * 20 + t) * 4) = bb;
            out[O_NMS_CLS + b * 20 + t] = rv[0];
        }
        __syncthreads();
        const float bx0 = bxs[0], by0 = bxs[1], bx1 = bxs[2], by1 = bxs[3];
        const float ab2 = fmaxf(bx1 - bx0, 0.f) * fmaxf(by1 - by0, 0.f);
        const int si = seli;
        for (int i = tid; i < 9216; i += 256) {
            const float4 qb = *(const float4*)(P + (size_t)i * 4);
            const float ix1 = fmaxf(bx0, qb.x), iy1 = fmaxf(by0, qb.y);
            const float ix2 = fminf(bx1, qb.z), iy2 = fminf(by1, qb.w);
            const float inter = fmaxf(ix2 - ix1, 0.f) * fmaxf(iy2 - iy1, 0.f);
            const float ar2 = fmaxf(qb.z - qb.x, 0.f) * fmaxf(qb.w - qb.y, 0.f);
            const float iou = inter / (ab2 + ar2 - inter + 1e-8f);
            if (iou > 0.3f || i == si) sv[i] = NEGV;
        }
        __syncthreads();
    }
}

// ---------------- ROI align -> flat [40][50176], col = c*49 + py*7 + px ----------------
__global__ __launch_bounds__(256) void k_roi(const float* __restrict__ fm,
        const int* __restrict__ img_id, const float* __restrict__ nreg,
        float* __restrict__ flat) {
    const int py = blockIdx.x, roi = blockIdx.y, b = blockIdx.z;
    const float* bx = nreg + (size_t)(b * 20 + roi) * 4;
    const float b0 = bx[0] * 0.0625f, b1 = bx[1] * 0.0625f;
    const float b2 = bx[2] * 0.0625f, b3 = bx[3] * 0.0625f;
    const float wd = fmaxf(b2 - b0, 0.f), hg = fmaxf(b3 - b1, 0.f);
    const float tyv = ((float)py + 0.5f) / 7.0f;
    const float ycv = fminf(fmaxf(b1 + hg * tyv, 0.f), 31.f);
    const float y0f = floorf(ycv);
    const int y0 = (int)y0f, y1 = min(y0 + 1, 31);
    const float ly = ycv - y0f, omly = 1.f - ly;
    const int bb = img_id[b];
    const float* fmb = fm + (size_t)bb * (32 * 32 * 1024);
    const size_t orow = (size_t)(b * 20 + roi) * 50176 + (size_t)py * 7;
    for (int px = 0; px < 7; ++px) {
        const float txv = ((float)px + 0.5f) / 7.0f;
        const float xcv = fminf(fmaxf(b0 + wd * txv, 0.f), 31.f);
        const float x0f = floorf(xcv);
        const int x0 = (int)x0f, x1 = min(x0 + 1, 31);
        const float lx = xcv - x0f, omlx = 1.f - lx;
        const int o00 = ((y0 * 32) + x0) << 10, o01 = ((y0 * 32) + x1) << 10;
        const int o10 = ((y1 * 32) + x0) << 10, o11 = ((y1 * 32) + x1) << 10;
        for (int u = 0; u < 4; ++u) {
            const int c = threadIdx.x + u * 256;
            const float v00 = fmb[o00 + c], v01 = fmb[o01 + c];
            const float v10 = fmb[o10 + c], v11 = fmb[o11 + c];
            const float val = ((v00 * omly) * omlx) + ((v01 * omly) * lx)
                            + ((v10 * ly) * omlx) + ((v11 * ly) * lx);
            flat[orow + (size_t)c * 49 + px] = val;
        }
    }
}

// ---------------- hf accumulator init (bias) ----------------
__global__ void k_hf_init(const float* __restrict__ fcb, float* __restrict__ hf) {
    const int i = blockIdx.x * 256 + threadIdx.x;
    if (i < 40 * 1024) hf[i] = fcb[i & 1023];
}

// ---------------- FC GEMM fp32: (40 pad 64) x 1024 x 50176, split-K=49, atomic acc ----------------
__global__ __launch_bounds__(256) void k_fc(const float* __restrict__ flat,
        const float* __restrict__ fcw, float* __restrict__ hf) {
    __shared__ __align__(16) float As[16][64];
    __shared__ __align__(16) float Bs2[16][64];
    const int tid = threadIdx.x;
    const int n0 = blockIdx.x * 64;
    const int kb = blockIdx.y * 1024;
    const int tx = tid & 15, ty = tid >> 4;
    const int lm = tid >> 2, lk4 = (tid & 3) * 4;
    const int lkb = tid >> 4, ln4 = (tid & 15) * 4;
    const float* arow = flat + (size_t)lm * 50176 + kb;
    float acc[4][4] = {{0.f}};
    for (int kq = 0; kq < 1024; kq += 16) {
        float4 av = make_float4(0.f, 0.f, 0.f, 0.f);
        if (lm < 40) av = *(const float4*)(arow + kq + lk4);
        const float4 bv = *(const float4*)(fcw + (size_t)(kb + kq + lkb) * 1024 + n0 + ln4);
        As[lk4 + 0][lm] = av.x; As[lk4 + 1][lm] = av.y; As[lk4 + 2][lm] = av.z; As[lk4 + 3][lm] = av.w;
        *(float4*)&Bs2[lkb][ln4] = bv;
        __syncthreads();
#pragma unroll
        for (int q8 = 0; q8 < 16; ++q8) {
            const float4 a4 = *(const float4*)(&As[q8][ty * 4]);
            const float4 b4 = *(const float4*)(&Bs2[q8][tx * 4]);
            acc[0][0] += a4.x*b4.x; acc[0][1] += a4.x*b4.y; acc[0][2] += a4.x*b4.z; acc[0][3] += a4.x*b4.w;
            acc[1][0] += a4.y*b4.x; acc[1][1] += a4.y*b4.y; acc[1][2] += a4.y*b4.z; acc[1][3] += a4.y*b4.w;
            acc[2][0] += a4.z*b4.x; acc[2][1] += a4.z*b4.y; acc[2][2] += a4.z*b4.z; acc[2][3] += a4.z*b4.w;
            acc[3][0] += a4.w*b4.x; acc[3][1] += a4.w*b4.y; acc[3][2] += a4.w*b4.z; acc[3][3] += a4.w*b4.w;
        }
        __syncthreads();
    }
#pragma unroll
    for (int rr = 0; rr < 4; ++rr) {
        const int m = ty * 4 + rr;
        if (m < 40) {
#pragma unroll
            for (int ss = 0; ss < 4; ++ss)
                atomicAdd(hf + (size_t)m * 1024 + n0 + tx * 4 + ss, acc[rr][ss]);
        }
    }
}

// ---------------- final heads ----------------
__global__ __launch_bounds__(64) void k_heads(const float* __restrict__ hf,
        const float* __restrict__ regw, const float* __restrict__ regb,
        const float* __restrict__ clsw, const float* __restrict__ clsb,
        float* __restrict__ out) {
    __shared__ __align__(16) float hrow[1024];
    const int m = blockIdx.x, tid = threadIdx.x;
    for (int i = tid * 4; i < 1024; i += 256) {
        const float4 v = *(const float4*)(hf + (size_t)m * 1024 + i);
        hrow[i + 0] = relu_(v.x); hrow[i + 1] = relu_(v.y);
        hrow[i + 2] = relu_(v.z); hrow[i + 3] = relu_(v.w);
    }
    __syncthreads();
    if (tid < 25) {
        float acc2 = 0.f;
        if (tid < 4) {
            for (int k = 0; k < 1024; ++k) acc2 += hrow[k] * regw[(size_t)k * 4 + tid];
            out[O_RCNN_REG + m * 4 + tid] = acc2 + regb[tid];
        } else {
            const int n = tid - 4;
            for (int k = 0; k < 1024; ++k) acc2 += hrow[k] * clsw[(size_t)k * 21 + n];
            out[O_RCNN_CLS + m * 21 + n] = acc2 + clsb[n];
        }
    }
}

extern "C" void kernel_launch(void* const* d_in, const int* in_sizes, int n_in,
                              void* d_out, int out_size, void* d_ws, size_t ws_size,
                              hipStream_t stream) {
    (void)in_sizes; (void)n_in; (void)out_size; (void)ws_size;
    const float* img       = (const float*)d_in[0];
    const int*   img_id    = (const int*)  d_in[1];
    const float* cnn_w     = (const float*)d_in[2];
    const float* cnn_b     = (const float*)d_in[3];
    const float* rpn_w     = (const float*)d_in[4];
    const float* rpn_b     = (const float*)d_in[5];
    const float* rpn_reg_w = (const float*)d_in[6];
    const float* rpn_reg_b = (const float*)d_in[7];
    const float* rpn_cls_w = (const float*)d_in[8];
    const float* rpn_cls_b = (const float*)d_in[9];
    const float* fc_w      = (const float*)d_in[10];
    const float* fc_b      = (const float*)d_in[11];
    const float* reg_w     = (const float*)d_in[12];
    const float* reg_b     = (const float*)d_in[13];
    const float* cls_w     = (const float*)d_in[14];
    const float* cls_b     = (const float*)d_in[15];
    float* out = (float*)d_out;
    float* ws  = (float*)d_ws;

    float* fm   = ws + W_FM;
    float* hbuf = ws + W_H;
    float* prop = ws + W_PROP;
    float* scr  = ws + W_SCR;
    float* flat = ws + W_FLAT;
    float* hf   = ws + W_HF;
    u16* a1h = (u16*)(ws + W_A1H);
    u16* a1l = (u16*)(ws + W_A1L);
    u16* b1h = (u16*)(ws + W_B1H);
    u16* b1l = (u16*)(ws + W_B1L);
    u16* fmh = (u16*)(ws + W_FMH);
    u16* fml = (u16*)(ws + W_FML);
    u16* b2h = (u16*)(ws + W_B2H);
    u16* b2l = (u16*)(ws + W_B2L);
    float* part = ws + W_PART;

    // conv1 path
    k_prep_a1<<<1536, 256, 0, stream>>>(img, a1h, a1l);
    k_split4<<<768, 256, 0, stream>>>(cnn_w, b1h, b1l, 196608);
    k_prep_w2<<<4608, 256, 0, stream>>>(rpn_w, b2h, b2l);
    k_gemm<0><<<dim3(16, 16, 1), 256, 0, stream>>>(a1h, a1l, b1h, b1l, cnn_b, fm,
                                                   768, 768, 24, 1024, 1);
    // rpn path
    k_split4<<<2048, 256, 0, stream>>>(fm, fmh, fml, 524288);
    k_gemm<1><<<dim3(16, 8, 2), 256, 0, stream>>>(fmh, fml, b2h, b2l, nullptr, part,
                                                  1024, 9216, 144, 512, 0);
    k_reduce<<<1024, 256, 0, stream>>>(part, rpn_b, hbuf);
    k_rpn_heads<<<2048, 64, 0, stream>>>(hbuf, rpn_reg_w, rpn_reg_b, rpn_cls_w, rpn_cls_b,
                                         out, prop, scr);
    k_nms<<<2, 256, 0, stream>>>(prop, scr, out);
    k_roi<<<dim3(7, 20, 2), 256, 0, stream>>>(fm, img_id, out + O_NMS_REG, flat);
    k_hf_init<<<(40 * 1024 + 255) / 256, 256, 0, stream>>>(fc_b, hf);
    k_fc<<<dim3(16, 49), 256, 0, stream>>>(flat, fc_w, hf);
    k_heads<<<40, 64, 0, stream>>>(hf, reg_w, reg_b, cls_w, cls_b, out);
}

// Round 3
// 749.336 us; speedup vs baseline: 1.8987x; 1.0993x over previous
//
#include <hip/hip_runtime.h>
#include <math.h>

// ---------------- problem constants ----------------
// B=2, IMG=512, FMC=1024, HID=512, A=9, NC=21, RED=16, POOL=7, TOP=20
// fm spatial 32x32. GEMMs: conv1 2048x1024x768, rpn 2048x512x9216, fc 40x1024x50176.

#define NEGV (-1e30f)

typedef unsigned short u16;
typedef float v4f __attribute__((ext_vector_type(4)));
typedef short short8 __attribute__((ext_vector_type(8)));

// output offsets (floats)
#define O_RPN_REG 0
#define O_RPN_CLS 73728
#define O_NMS_REG 92160
#define O_NMS_CLS 92320
#define O_RCNN_REG 92360
#define O_RCNN_CLS 92520
#define O_ANCH 93360

// workspace offsets (floats)
#define W_FM   0u            // 2048*1024 fm NHWC fp32
#define W_H    2097152u      // (unused now)
#define W_PROP 3145728u      // 2*9216*4
#define W_SCR  3219456u      // 2*9216
#define W_FLAT 3237888u      // 40*50176
#define W_HF   5244928u      // 40*1024
#define W_A1H  5285888u      // 2048*768 u16 -> 786432 floats
#define W_A1L  6072320u
#define W_B1H  6858752u      // 1024*768 u16 -> 393216 floats
#define W_B1L  7251968u
#define W_FMH  7645184u      // 2048*1024 u16 -> 1048576 floats
#define W_FML  8693760u
#define W_B2H  9742336u      // 512*9216 u16 -> 2359296 floats
#define W_B2L  12101632u
#define W_PART 14460928u     // 2 * 2048*512 fp32
// end = 16,558,080 floats = 66.2 MB

static __device__ __forceinline__ float relu_(float v) { return fmaxf(v, 0.0f); }

// fp32 -> bf16 hi/lo split (RTNE)
static __device__ __forceinline__ u16 bf16_rtne(float x) {
    unsigned int u = __float_as_uint(x);
    unsigned int r = u + 0x7fffu + ((u >> 16) & 1u);
    return (u16)(r >> 16);
}
static __device__ __forceinline__ void split2(float x, u16& h, u16& l) {
    h = bf16_rtne(x);
    const float hf = __uint_as_float(((unsigned int)h) << 16);
    l = bf16_rtne(x - hf);
}
// split 8 fp32 (register array) -> 16B hi + 16B lo LDS stores
static __device__ __forceinline__ void split8_store(const float* v, u16* dsth, u16* dstl) {
    uint4 H, Lo;
    u16 h0, l0, h1, l1;
    split2(v[0], h0, l0); split2(v[1], h1, l1);
    H.x = (unsigned)h0 | ((unsigned)h1 << 16); Lo.x = (unsigned)l0 | ((unsigned)l1 << 16);
    split2(v[2], h0, l0); split2(v[3], h1, l1);
    H.y = (unsigned)h0 | ((unsigned)h1 << 16); Lo.y = (unsigned)l0 | ((unsigned)l1 << 16);
    split2(v[4], h0, l0); split2(v[5], h1, l1);
    H.z = (unsigned)h0 | ((unsigned)h1 << 16); Lo.z = (unsigned)l0 | ((unsigned)l1 << 16);
    split2(v[6], h0, l0); split2(v[7], h1, l1);
    H.w = (unsigned)h0 | ((unsigned)h1 << 16); Lo.w = (unsigned)l0 | ((unsigned)l1 << 16);
    *(uint4*)dsth = H; *(uint4*)dstl = Lo;
}

// anchor half-extents, bit-matching numpy f64 -> f32
static __device__ __forceinline__ void anchor_wh(int a, float& w2, float& h2) {
    double s = (a < 3) ? 64.0 : (a < 6) ? 128.0 : 256.0;
    int rm = a - (a / 3) * 3;
    double r = (rm == 0) ? 0.5 : (rm == 1) ? 1.0 : 2.0;
    double sq = sqrt(r);
    w2 = (float)(s * sq) * 0.5f;
    h2 = (float)(s / sq) * 0.5f;
}

// ---------------- prep: conv1 im2col A (bf16 hi/lo) ----------------
__global__ void k_prep_a1(const float* __restrict__ img, u16* __restrict__ a1h, u16* __restrict__ a1l) {
    const int idx = blockIdx.x * 256 + threadIdx.x;        // 393216
    const int m = idx / 192, kq = (idx - m * 192) * 4;
    const int b = m >> 10, i = (m >> 5) & 31, j = m & 31;
    const int c = kq >> 8, rem = kq & 255, y = rem >> 4, x = rem & 15;
    const float4 v = *(const float4*)(img + ((size_t)((b * 3 + c) * 512 + i * 16 + y)) * 512 + j * 16 + x);
    ushort4 H, Lo;
    split2(v.x, H.x, Lo.x); split2(v.y, H.y, Lo.y);
    split2(v.z, H.z, Lo.z); split2(v.w, H.w, Lo.w);
    *(ushort4*)(a1h + (size_t)idx * 4) = H;
    *(ushort4*)(a1l + (size_t)idx * 4) = Lo;
}

// ---------------- prep: generic fp32 -> bf16 hi/lo ----------------
__global__ void k_split4(const float* __restrict__ src, u16* __restrict__ h, u16* __restrict__ l, int n4) {
    const int idx = blockIdx.x * 256 + threadIdx.x;
    if (idx >= n4) return;
    const float4 v = *(const float4*)(src + (size_t)idx * 4);
    ushort4 H, Lo;
    split2(v.x, H.x, Lo.x); split2(v.y, H.y, Lo.y);
    split2(v.z, H.z, Lo.z); split2(v.w, H.w, Lo.w);
    *(ushort4*)(h + (size_t)idx * 4) = H;
    *(ushort4*)(l + (size_t)idx * 4) = Lo;
}

// ---------------- prep: rpn weights (512,1024,3,3) -> B2[oc][d*1024+ic] bf16 hi/lo ----------------
__global__ void k_prep_w2(const float* __restrict__ w, u16* __restrict__ bh, u16* __restrict__ bl) {
    const int idx = blockIdx.x * 256 + threadIdx.x;        // 1,179,648
    const int oc = idx / 2304, r = idx - oc * 2304, d = r >> 8, ic4 = (r & 255) * 4;
    const float* p = w + (size_t)oc * 9216 + (size_t)ic4 * 9 + d;
    float4 v; v.x = p[0]; v.y = p[9]; v.z = p[18]; v.w = p[27];
    ushort4 H, Lo;
    split2(v.x, H.x, Lo.x); split2(v.y, H.y, Lo.y);
    split2(v.z, H.z, Lo.z); split2(v.w, H.w, Lo.w);
    const size_t o = (size_t)oc * 9216 + d * 1024 + ic4;
    *(ushort4*)(bh + o) = H;
    *(ushort4*)(bl + o) = Lo;
}

// ---------------- MFMA bf16x3 GEMM (conv1 / rpn) ----------------
// Block tile 128(M) x 64(N), 256 thr = 4 waves, wave tile 64x32, K-chunk 32.
// MODE 0: A linear rows; also writes bf16 hi/lo split of C when outH!=null.
// MODE 1: rpn gather from fm (bf16 h/l [2048][1024]); split-K via blockIdx.z.
template<int MODE>
__global__ __launch_bounds__(256, 1) void k_gemm(
        const u16* __restrict__ Agh, const u16* __restrict__ Agl,
        const u16* __restrict__ Bgh, const u16* __restrict__ Bgl,
        const float* __restrict__ bias, float* __restrict__ Cout,
        const int KA, const int KB, const int nchunk, const int ldc, const int do_bias_relu,
        u16* __restrict__ outH, u16* __restrict__ outL) {
    __shared__ __align__(16) u16 AsH[128 * 32];
    __shared__ __align__(16) u16 AsL[128 * 32];
    __shared__ __align__(16) u16 BsH[64 * 32];
    __shared__ __align__(16) u16 BsL[64 * 32];
    const int tid = threadIdx.x;
    const int w = tid >> 6, L = tid & 63;
    const int q = L >> 4, lr = L & 15;
    const int wm = w >> 1, wn = w & 1;
    const int m0 = blockIdx.x * 128, n0 = blockIdx.y * 64;
    const int icoff = blockIdx.z * 512;
    float* C = Cout + (MODE == 1 ? (size_t)blockIdx.z * (2048u * 512u) : (size_t)0);
    const int seg = L & 3, rsub = L >> 2;

    u16* ldst[6];
    const u16* gbase[6];
    int arow_b[6], arow_i[6], arow_j[6];
    int kindv[6];
#pragma unroll
    for (int s = 0; s < 6; ++s) {
        const int idx = w * 6 + s;
        int kind, inst;
        if (idx < 8)       { kind = 0; inst = idx; }
        else if (idx < 16) { kind = 1; inst = idx - 8; }
        else if (idx < 20) { kind = 2; inst = idx - 16; }
        else               { kind = 3; inst = idx - 20; }
        kindv[s] = kind;
        const int r = inst * 16 + rsub;
        u16* lb = (kind == 0) ? AsH : (kind == 1) ? AsL : (kind == 2) ? BsH : BsL;
        ldst[s] = lb + r * 32 + seg * 8;
        arow_b[s] = 0; arow_i[s] = 0; arow_j[s] = 0;
        if (kind >= 2) {
            const u16* gb = (kind == 2) ? Bgh : Bgl;
            gbase[s] = gb + (size_t)(n0 + r) * KB + seg * 8;
        } else if (MODE == 0) {
            const u16* gb = (kind == 0) ? Agh : Agl;
            gbase[s] = gb + (size_t)(m0 + r) * KA + seg * 8;
        } else {
            const int m = m0 + r;
            arow_b[s] = m >> 10; arow_i[s] = (m >> 5) & 31; arow_j[s] = m & 31;
            gbase[s] = (kind == 0) ? Agh : Agl;
        }
    }

    v4f acc[4][2];
#pragma unroll
    for (int t = 0; t < 4; ++t)
#pragma unroll
        for (int u2 = 0; u2 < 2; ++u2) acc[t][u2] = (v4f){0.f, 0.f, 0.f, 0.f};

    uint4 ubuf[6];
    bool okbuf[6];

#define LOAD6(c_) do { \
    int d_, ic_, kB_; \
    if (MODE == 0) { kB_ = (c_) * 32; d_ = 0; ic_ = kB_; } \
    else { d_ = (c_) >> 4; ic_ = icoff + ((c_) & 15) * 32; kB_ = d_ * 1024 + ic_; } \
    const int di_ = d_ / 3, dj_ = d_ - di_ * 3; \
    _Pragma("unroll") \
    for (int s = 0; s < 6; ++s) { \
        if (kindv[s] >= 2) { ubuf[s] = *(const uint4*)(gbase[s] + kB_); okbuf[s] = true; } \
        else if (MODE == 0) { ubuf[s] = *(const uint4*)(gbase[s] + ic_); okbuf[s] = true; } \
        else { \
            const int y_ = arow_i[s] + di_ - 1, x_ = arow_j[s] + dj_ - 1; \
            const bool ok_ = ((unsigned)y_ < 32u) && ((unsigned)x_ < 32u); \
            const int yc_ = ok_ ? y_ : 0, xc_ = ok_ ? x_ : 0; \
            ubuf[s] = *(const uint4*)(gbase[s] + (size_t)(((arow_b[s] * 32 + yc_) * 32 + xc_)) * 1024 + ic_ + seg * 8); \
            okbuf[s] = ok_; \
        } \
    } \
} while (0)

    LOAD6(0);
    for (int c = 0; c < nchunk; ++c) {
        __syncthreads();
#pragma unroll
        for (int s = 0; s < 6; ++s) {
            uint4 v = ubuf[s];
            if (MODE == 1 && !okbuf[s]) { v.x = 0u; v.y = 0u; v.z = 0u; v.w = 0u; }
            *(uint4*)ldst[s] = v;
        }
        __syncthreads();
        if (c + 1 < nchunk) LOAD6(c + 1);
        short8 ah[4], al[4], bh[2], bl[2];
#pragma unroll
        for (int t = 0; t < 4; ++t) {
            ah[t] = *(const short8*)(AsH + (wm * 64 + t * 16 + lr) * 32 + q * 8);
            al[t] = *(const short8*)(AsL + (wm * 64 + t * 16 + lr) * 32 + q * 8);
        }
#pragma unroll
        for (int u2 = 0; u2 < 2; ++u2) {
            bh[u2] = *(const short8*)(BsH + (wn * 32 + u2 * 16 + lr) * 32 + q * 8);
            bl[u2] = *(const short8*)(BsL + (wn * 32 + u2 * 16 + lr) * 32 + q * 8);
        }
#pragma unroll
        for (int t = 0; t < 4; ++t)
#pragma unroll
            for (int u2 = 0; u2 < 2; ++u2) {
                acc[t][u2] = __builtin_amdgcn_mfma_f32_16x16x32_bf16(ah[t], bh[u2], acc[t][u2], 0, 0, 0);
                acc[t][u2] = __builtin_amdgcn_mfma_f32_16x16x32_bf16(ah[t], bl[u2], acc[t][u2], 0, 0, 0);
                acc[t][u2] = __builtin_amdgcn_mfma_f32_16x16x32_bf16(al[t], bh[u2], acc[t][u2], 0, 0, 0);
            }
    }
#undef LOAD6

#pragma unroll
    for (int t = 0; t < 4; ++t) {
        const int row = m0 + wm * 64 + t * 16 + q * 4;
#pragma unroll
        for (int u2 = 0; u2 < 2; ++u2) {
            const int col = n0 + wn * 32 + u2 * 16 + lr;
            const float bv = do_bias_relu ? bias[col] : 0.f;
#pragma unroll
            for (int r = 0; r < 4; ++r) {
                float vv = acc[t][u2][r];
                if (do_bias_relu) vv = relu_(vv + bv);
                C[(size_t)(row + r) * ldc + col] = vv;
                if (MODE == 0 && outH != nullptr) {
                    u16 hh, ll; split2(vv, hh, ll);
                    outH[(size_t)(row + r) * 1024 + col] = hh;
                    outL[(size_t)(row + r) * 1024 + col] = ll;
                }
            }
        }
    }
}

// ---------------- rpn heads (1x1 convs) + split-K reduce + anchors + proposals ----------------
__global__ __launch_bounds__(64) void k_rpn_heads(const float* __restrict__ part,
        const float* __restrict__ rpnb,
        const float* __restrict__ regw, const float* __restrict__ regb,
        const float* __restrict__ clsw, const float* __restrict__ clsb,
        float* __restrict__ out, float* __restrict__ prop, float* __restrict__ scr) {
    __shared__ __align__(16) float hrow[512];
    const int m = blockIdx.x, tid = threadIdx.x;
    const int b = m >> 10, qd = m & 1023, ii = qd >> 5, jj = qd & 31;
    for (int i = tid * 4; i < 512; i += 256) {
        const float4 p0 = *(const float4*)(part + (size_t)m * 512 + i);
        const float4 p1 = *(const float4*)(part + (size_t)(2048 * 512) + (size_t)m * 512 + i);
        const float4 bb = *(const float4*)(rpnb + i);
        float4 o;
        o.x = relu_(p0.x + p1.x + bb.x); o.y = relu_(p0.y + p1.y + bb.y);
        o.z = relu_(p0.z + p1.z + bb.z); o.w = relu_(p0.w + p1.w + bb.w);
        *(float4*)&hrow[i] = o;
    }
    __syncthreads();
    if (tid < 45) {
        const int isreg = (tid < 36);
        const float* wp = isreg ? (regw + (size_t)tid * 512) : (clsw + (size_t)(tid - 36) * 512);
        float acc2 = isreg ? regb[tid] : clsb[tid - 36];
        for (int k = 0; k < 512; k += 4) {
            const float4 wv = *(const float4*)(wp + k);
            acc2 += hrow[k + 0] * wv.x; acc2 += hrow[k + 1] * wv.y;
            acc2 += hrow[k + 2] * wv.z; acc2 += hrow[k + 3] * wv.w;
        }
        if (isreg) {
            out[O_RPN_REG + (size_t)b * 36864 + qd * 36 + tid] = acc2;
            const int a = tid >> 2, cc = tid & 3;
            float w2, h2; anchor_wh(a, w2, h2);
            const float cx = ((float)jj + 0.5f) * 16.f, cy = ((float)ii + 0.5f) * 16.f;
            const float av = (cc == 0) ? cx - w2 : (cc == 1) ? cy - h2 : (cc == 2) ? cx + w2 : cy + h2;
            prop[(size_t)b * 36864 + qd * 36 + tid] = acc2 + av;
        } else {
            const int n = tid - 36;
            out[O_RPN_CLS + (size_t)b * 9216 + qd * 9 + n] = acc2;
            scr[(size_t)b * 9216 + qd * 9 + n] = acc2;
        }
    }
    if (b == 0 && tid >= 48 && tid < 57) {
        const int a = tid - 48;
        float w2, h2; anchor_wh(a, w2, h2);
        const float cx = ((float)jj + 0.5f) * 16.f, cy = ((float)ii + 0.5f) * 16.f;
        const float4 av4 = make_float4(cx - w2, cy - h2, cx + w2, cy + h2);
        *(float4*)(out + O_ANCH + (size_t)(qd * 9 + a) * 4) = av4;
    }
}

// ---------------- NMS: boxes+scores in registers, 1024 thr, shuffle reduce ----------------
__global__ __launch_bounds__(1024) void k_nms2(const float* __restrict__ prop,
        const float* __restrict__ scr, float* __restrict__ out) {
    __shared__ float wv_[16];
    __shared__ int wi_[16];
    __shared__ float bxs[4];
    __shared__ int sel_s;
    __shared__ float sc_s;
    const int b = blockIdx.x, tid = threadIdx.x;
    const int lane = tid & 63, wid = tid >> 6;
    const float* P = prop + (size_t)b * 36864;
    float4 bx[9]; float sv[9];
#pragma unroll
    for (int k = 0; k < 9; ++k) {
        const int i = tid + 1024 * k;
        bx[k] = *(const float4*)(P + (size_t)i * 4);
        sv[k] = scr[b * 9216 + i];
    }
    for (int t = 0; t < 20; ++t) {
        float bv = -3.4e38f; int bi = 0x40000000;
#pragma unroll
        for (int k = 0; k < 9; ++k)
            if (sv[k] > bv) { bv = sv[k]; bi = tid + 1024 * k; }   // k ascending -> smallest idx kept
#pragma unroll
        for (int off = 32; off > 0; off >>= 1) {
            const float ov = __shfl_xor(bv, off);
            const int oi = __shfl_xor(bi, off);
            if (ov > bv || (ov == bv && oi < bi)) { bv = ov; bi = oi; }
        }
        if (lane == 0) { wv_[wid] = bv; wi_[wid] = bi; }
        __syncthreads();
        if (tid == 0) {
            float rb = wv_[0]; int ri = wi_[0];
            for (int j = 1; j < 16; ++j)
                if (wv_[j] > rb || (wv_[j] == rb && wi_[j] < ri)) { rb = wv_[j]; ri = wi_[j]; }
            sel_s = ri; sc_s = rb;
        }
        __syncthreads();
        const int sel = sel_s;
        if (tid == (sel & 1023)) {
            const int k = sel >> 10;
            const float4 bb = bx[k];
            bxs[0] = bb.x; bxs[1] = bb.y; bxs[2] = bb.z; bxs[3] = bb.w;
            sv[k] = NEGV;
            *(float4*)(out + O_NMS_REG + (size_t)(b * 20 + t) * 4) = bb;
            out[O_NMS_CLS + b * 20 + t] = sc_s;
        }
        __syncthreads();
        const float bx0 = bxs[0], by0 = bxs[1], bx1 = bxs[2], by1 = bxs[3];
        const float ab2 = fmaxf(bx1 - bx0, 0.f) * fmaxf(by1 - by0, 0.f);
#pragma unroll
        for (int k = 0; k < 9; ++k) {
            const float ix1 = fmaxf(bx0, bx[k].x), iy1 = fmaxf(by0, bx[k].y);
            const float ix2 = fminf(bx1, bx[k].z), iy2 = fminf(by1, bx[k].w);
            const float inter = fmaxf(ix2 - ix1, 0.f) * fmaxf(iy2 - iy1, 0.f);
            const float ar2 = fmaxf(bx[k].z - bx[k].x, 0.f) * fmaxf(bx[k].w - bx[k].y, 0.f);
            const float iou = inter / (ab2 + ar2 - inter + 1e-8f);
            if (iou > 0.3f) sv[k] = NEGV;
        }
    }
}

// ---------------- ROI align -> flat [40][50176], col = c*49 + py*7 + px ----------------
__global__ __launch_bounds__(256) void k_roi(const float* __restrict__ fm,
        const int* __restrict__ img_id, const float* __restrict__ nreg,
        float* __restrict__ flat) {
    const int py = blockIdx.x, roi = blockIdx.y, b = blockIdx.z;
    const float* bx = nreg + (size_t)(b * 20 + roi) * 4;
    const float b0 = bx[0] * 0.0625f, b1 = bx[1] * 0.0625f;
    const float b2 = bx[2] * 0.0625f, b3 = bx[3] * 0.0625f;
    const float wd = fmaxf(b2 - b0, 0.f), hg = fmaxf(b3 - b1, 0.f);
    const float tyv = ((float)py + 0.5f) / 7.0f;
    const float ycv = fminf(fmaxf(b1 + hg * tyv, 0.f), 31.f);
    const float y0f = floorf(ycv);
    const int y0 = (int)y0f, y1 = min(y0 + 1, 31);
    const float ly = ycv - y0f, omly = 1.f - ly;
    const int bb = img_id[b];
    const float* fmb = fm + (size_t)bb * (32 * 32 * 1024);
    const size_t orow = (size_t)(b * 20 + roi) * 50176 + (size_t)py * 7;
    for (int px = 0; px < 7; ++px) {
        const float txv = ((float)px + 0.5f) / 7.0f;
        const float xcv = fminf(fmaxf(b0 + wd * txv, 0.f), 31.f);
        const float x0f = floorf(xcv);
        const int x0 = (int)x0f, x1 = min(x0 + 1, 31);
        const float lx = xcv - x0f, omlx = 1.f - lx;
        const int o00 = ((y0 * 32) + x0) << 10, o01 = ((y0 * 32) + x1) << 10;
        const int o10 = ((y1 * 32) + x0) << 10, o11 = ((y1 * 32) + x1) << 10;
        for (int u = 0; u < 4; ++u) {
            const int c = threadIdx.x + u * 256;
            const float v00 = fmb[o00 + c], v01 = fmb[o01 + c];
            const float v10 = fmb[o10 + c], v11 = fmb[o11 + c];
            const float val = ((v00 * omly) * omlx) + ((v01 * omly) * lx)
                            + ((v10 * ly) * omlx) + ((v11 * ly) * lx);
            flat[orow + (size_t)c * 49 + px] = val;
        }
    }
}

// ---------------- hf accumulator init (bias) ----------------
__global__ void k_hf_init(const float* __restrict__ fcb, float* __restrict__ hf) {
    const int i = blockIdx.x * 256 + threadIdx.x;
    if (i < 40 * 1024) hf[i] = fcb[i & 1023];
}

// ---------------- FC GEMM MFMA bf16x3: 40(pad48) x 1024 x 50176 ----------------
// grid (4 n-tiles of 256, 98 k-splits of 512). In-kernel fp32->bf16 split of both
// operands (weights 205 MB read exactly once). atomicAdd fp32 into hf.
// LDS layout [oct][row][8k] -> all b128 LDS traffic conflict-free.
__global__ __launch_bounds__(256, 2) void k_fc_mfma(const float* __restrict__ flat,
        const float* __restrict__ fcw, float* __restrict__ hf) {
    __shared__ __align__(16) u16 AsH[4 * 48 * 8];
    __shared__ __align__(16) u16 AsL[4 * 48 * 8];
    __shared__ __align__(16) u16 BsH[4 * 256 * 8];
    __shared__ __align__(16) u16 BsL[4 * 256 * 8];
    const int tid = threadIdx.x;
    const int w = tid >> 6, L = tid & 63, q = L >> 4, lr = L & 15;
    const int n0 = blockIdx.x * 256, kb = blockIdx.y * 512;
    // zero-pad A rows 40..47 (persist across chunks)
    if (tid < 32) {
        const int oct = tid >> 3, m = 40 + (tid & 7);
        *(uint4*)(AsH + (oct * 48 + m) * 8) = make_uint4(0, 0, 0, 0);
        *(uint4*)(AsL + (oct * 48 + m) * 8) = make_uint4(0, 0, 0, 0);
    }
    const int am = tid >> 2, aoct = tid & 3;              // A task (tid<160)
    const float* abase = flat + (size_t)am * 50176 + kb + aoct * 8;
    const float* bcol = fcw + n0 + tid;

    v4f acc[3][4];
#pragma unroll
    for (int mt = 0; mt < 3; ++mt)
#pragma unroll
        for (int nt = 0; nt < 4; ++nt) acc[mt][nt] = (v4f){0.f, 0.f, 0.f, 0.f};

    float areg[8];
    float breg[4][8];

#define LOADF(c_) do { \
    if (tid < 160) { \
        const float4 u_ = *(const float4*)(abase + (c_) * 32); \
        const float4 v_ = *(const float4*)(abase + (c_) * 32 + 4); \
        areg[0] = u_.x; areg[1] = u_.y; areg[2] = u_.z; areg[3] = u_.w; \
        areg[4] = v_.x; areg[5] = v_.y; areg[6] = v_.z; areg[7] = v_.w; \
    } \
    _Pragma("unroll") \
    for (int o_ = 0; o_ < 4; ++o_) \
        _Pragma("unroll") \
        for (int j_ = 0; j_ < 8; ++j_) \
            breg[o_][j_] = bcol[(size_t)(kb + (c_) * 32 + o_ * 8 + j_) * 1024]; \
} while (0)

    LOADF(0);
    for (int c = 0; c < 16; ++c) {
        __syncthreads();
        if (tid < 160)
            split8_store(areg, AsH + (aoct * 48 + am) * 8, AsL + (aoct * 48 + am) * 8);
#pragma unroll
        for (int o = 0; o < 4; ++o)
            split8_store(breg[o], BsH + (o * 256 + tid) * 8, BsL + (o * 256 + tid) * 8);
        __syncthreads();
        if (c + 1 < 16) LOADF(c + 1);
        short8 ah[3], al[3], bh2[4], bl2[4];
#pragma unroll
        for (int mt = 0; mt < 3; ++mt) {
            ah[mt] = *(const short8*)(AsH + (q * 48 + mt * 16 + lr) * 8);
            al[mt] = *(const short8*)(AsL + (q * 48 + mt * 16 + lr) * 8);
        }
#pragma unroll
        for (int nt = 0; nt < 4; ++nt) {
            bh2[nt] = *(const short8*)(BsH + (q * 256 + w * 64 + nt * 16 + lr) * 8);
            bl2[nt] = *(const short8*)(BsL + (q * 256 + w * 64 + nt * 16 + lr) * 8);
        }
#pragma unroll
        for (int mt = 0; mt < 3; ++mt)
#pragma unroll
            for (int nt = 0; nt < 4; ++nt) {
                acc[mt][nt] = __builtin_amdgcn_mfma_f32_16x16x32_bf16(ah[mt], bh2[nt], acc[mt][nt], 0, 0, 0);
                acc[mt][nt] = __builtin_amdgcn_mfma_f32_16x16x32_bf16(ah[mt], bl2[nt], acc[mt][nt], 0, 0, 0);
                acc[mt][nt] = __builtin_amdgcn_mfma_f32_16x16x32_bf16(al[mt], bh2[nt], acc[mt][nt], 0, 0, 0);
            }
    }
#undef LOADF

#pragma unroll
    for (int mt = 0; mt < 3; ++mt) {
#pragma unroll
        for (int nt = 0; nt < 4; ++nt) {
#pragma unroll
            for (int r = 0; r < 4; ++r) {
                const int row = mt * 16 + q * 4 + r;
                if (row < 40)
                    atomicAdd(hf + (size_t)row * 1024 + n0 + w * 64 + nt * 16 + lr, acc[mt][nt][r]);
            }
        }
    }
}

// ---------------- final heads ----------------
__global__ __launch_bounds__(64) void k_heads(const float* __restrict__ hf,
        const float* __restrict__ regw, const float* __restrict__ regb,
        const float* __restrict__ clsw, const float* __restrict__ clsb,
        float* __restrict__ out) {
    __shared__ __align__(16) float hrow[1024];
    const int m = blockIdx.x, tid = threadIdx.x;
    for (int i = tid * 4; i < 1024; i += 256) {
        const float4 v = *(const float4*)(hf + (size_t)m * 1024 + i);
        hrow[i + 0] = relu_(v.x); hrow[i + 1] = relu_(v.y);
        hrow[i + 2] = relu_(v.z); hrow[i + 3] = relu_(v.w);
    }
    __syncthreads();
    if (tid < 25) {
        float acc2 = 0.f;
        if (tid < 4) {
            for (int k = 0; k < 1024; ++k) acc2 += hrow[k] * regw[(size_t)k * 4 + tid];
            out[O_RCNN_REG + m * 4 + tid] = acc2 + regb[tid];
        } else {
            const int n = tid - 4;
            for (int k = 0; k < 1024; ++k) acc2 += hrow[k] * clsw[(size_t)k * 21 + n];
            out[O_RCNN_CLS + m * 21 + n] = acc2 + clsb[n];
        }
    }
}

extern "C" void kernel_launch(void* const* d_in, const int* in_sizes, int n_in,
                              void* d_out, int out_size, void* d_ws, size_t ws_size,
                              hipStream_t stream) {
    (void)in_sizes; (void)n_in; (void)out_size; (void)ws_size;
    const float* img       = (const float*)d_in[0];
    const int*   img_id    = (const int*)  d_in[1];
    const float* cnn_w     = (const float*)d_in[2];
    const float* cnn_b     = (const float*)d_in[3];
    const float* rpn_w     = (const float*)d_in[4];
    const float* rpn_b     = (const float*)d_in[5];
    const float* rpn_reg_w = (const float*)d_in[6];
    const float* rpn_reg_b = (const float*)d_in[7];
    const float* rpn_cls_w = (const float*)d_in[8];
    const float* rpn_cls_b = (const float*)d_in[9];
    const float* fc_w      = (const float*)d_in[10];
    const float* fc_b      = (const float*)d_in[11];
    const float* reg_w     = (const float*)d_in[12];
    const float* reg_b     = (const float*)d_in[13];
    const float* cls_w     = (const float*)d_in[14];
    const float* cls_b     = (const float*)d_in[15];
    float* out = (float*)d_out;
    float* ws  = (float*)d_ws;

    float* fm   = ws + W_FM;
    float* prop = ws + W_PROP;
    float* scr  = ws + W_SCR;
    float* flat = ws + W_FLAT;
    float* hf   = ws + W_HF;
    u16* a1h = (u16*)(ws + W_A1H);
    u16* a1l = (u16*)(ws + W_A1L);
    u16* b1h = (u16*)(ws + W_B1H);
    u16* b1l = (u16*)(ws + W_B1L);
    u16* fmh = (u16*)(ws + W_FMH);
    u16* fml = (u16*)(ws + W_FML);
    u16* b2h = (u16*)(ws + W_B2H);
    u16* b2l = (u16*)(ws + W_B2L);
    float* part = ws + W_PART;

    // conv1 path (epilogue also writes fmh/fml bf16 split)
    k_prep_a1<<<1536, 256, 0, stream>>>(img, a1h, a1l);
    k_split4<<<768, 256, 0, stream>>>(cnn_w, b1h, b1l, 196608);
    k_prep_w2<<<4608, 256, 0, stream>>>(rpn_w, b2h, b2l);
    k_gemm<0><<<dim3(16, 16, 1), 256, 0, stream>>>(a1h, a1l, b1h, b1l, cnn_b, fm,
                                                   768, 768, 24, 1024, 1, fmh, fml);
    // rpn path
    k_gemm<1><<<dim3(16, 8, 2), 256, 0, stream>>>(fmh, fml, b2h, b2l, nullptr, part,
                                                  1024, 9216, 144, 512, 0, nullptr, nullptr);
    k_rpn_heads<<<2048, 64, 0, stream>>>(part, rpn_b, rpn_reg_w, rpn_reg_b, rpn_cls_w, rpn_cls_b,
                                         out, prop, scr);
    k_nms2<<<2, 1024, 0, stream>>>(prop, scr, out);
    k_roi<<<dim3(7, 20, 2), 256, 0, stream>>>(fm, img_id, out + O_NMS_REG, flat);
    k_hf_init<<<160, 256, 0, stream>>>(fc_b, hf);
    k_fc_mfma<<<dim3(4, 98), 256, 0, stream>>>(flat, fc_w, hf);
    k_heads<<<40, 64, 0, stream>>>(hf, reg_w, reg_b, cls_w, cls_b, out);
}

// Round 4
// 672.147 us; speedup vs baseline: 2.1168x; 1.1148x over previous
//
#include <hip/hip_runtime.h>
#include <math.h>

// ---------------- problem constants ----------------
// B=2, IMG=512, FMC=1024, HID=512, A=9, NC=21, RED=16, POOL=7, TOP=20
// fm spatial 32x32. GEMMs: conv1 2048x1024x768, rpn 2048x512x9216, fc 40x1024x50176.

#define NEGV (-1e30f)

typedef unsigned short u16;
typedef float v4f __attribute__((ext_vector_type(4)));
typedef short short8 __attribute__((ext_vector_type(8)));

// output offsets (floats)
#define O_RPN_REG 0
#define O_RPN_CLS 73728
#define O_NMS_REG 92160
#define O_NMS_CLS 92320
#define O_RCNN_REG 92360
#define O_RCNN_CLS 92520
#define O_ANCH 93360

// workspace offsets (floats)
#define W_FM   0u            // 2048*1024 fm NHWC fp32
#define W_H    2097152u      // (unused)
#define W_PROP 3145728u      // 2*9216*4
#define W_SCR  3219456u      // 2*9216
#define W_FLAT 3237888u      // 40*50176
#define W_HF   5244928u      // 40*1024
#define W_A1H  5285888u      // 2048*768 u16 -> 786432 floats
#define W_A1L  6072320u
#define W_B1H  6858752u      // 1024*768 u16 -> 393216 floats
#define W_B1L  7251968u
#define W_FMH  7645184u      // 2048*1024 u16 -> 1048576 floats
#define W_FML  8693760u
#define W_B2H  9742336u      // 512*9216 u16 -> 2359296 floats
#define W_B2L  12101632u
#define W_PART 14460928u     // 2 * 2048*512 fp32
// end = 16,558,080 floats = 66.2 MB

static __device__ __forceinline__ float relu_(float v) { return fmaxf(v, 0.0f); }

// fp32 -> bf16 hi/lo split (RTNE)
static __device__ __forceinline__ u16 bf16_rtne(float x) {
    unsigned int u = __float_as_uint(x);
    unsigned int r = u + 0x7fffu + ((u >> 16) & 1u);
    return (u16)(r >> 16);
}
static __device__ __forceinline__ void split2(float x, u16& h, u16& l) {
    h = bf16_rtne(x);
    const float hf = __uint_as_float(((unsigned int)h) << 16);
    l = bf16_rtne(x - hf);
}
// split 8 fp32 (register array) -> 16B hi + 16B lo LDS stores
static __device__ __forceinline__ void split8_store(const float* v, u16* dsth, u16* dstl) {
    uint4 H, Lo;
    u16 h0, l0, h1, l1;
    split2(v[0], h0, l0); split2(v[1], h1, l1);
    H.x = (unsigned)h0 | ((unsigned)h1 << 16); Lo.x = (unsigned)l0 | ((unsigned)l1 << 16);
    split2(v[2], h0, l0); split2(v[3], h1, l1);
    H.y = (unsigned)h0 | ((unsigned)h1 << 16); Lo.y = (unsigned)l0 | ((unsigned)l1 << 16);
    split2(v[4], h0, l0); split2(v[5], h1, l1);
    H.z = (unsigned)h0 | ((unsigned)h1 << 16); Lo.z = (unsigned)l0 | ((unsigned)l1 << 16);
    split2(v[6], h0, l0); split2(v[7], h1, l1);
    H.w = (unsigned)h0 | ((unsigned)h1 << 16); Lo.w = (unsigned)l0 | ((unsigned)l1 << 16);
    *(uint4*)dsth = H; *(uint4*)dstl = Lo;
}

// anchor half-extents, bit-matching numpy f64 -> f32
static __device__ __forceinline__ void anchor_wh(int a, float& w2, float& h2) {
    double s = (a < 3) ? 64.0 : (a < 6) ? 128.0 : 256.0;
    int rm = a - (a / 3) * 3;
    double r = (rm == 0) ? 0.5 : (rm == 1) ? 1.0 : 2.0;
    double sq = sqrt(r);
    w2 = (float)(s * sq) * 0.5f;
    h2 = (float)(s / sq) * 0.5f;
}

// ---------------- prep: conv1 im2col A (bf16 hi/lo) ----------------
__global__ void k_prep_a1(const float* __restrict__ img, u16* __restrict__ a1h, u16* __restrict__ a1l) {
    const int idx = blockIdx.x * 256 + threadIdx.x;        // 393216
    const int m = idx / 192, kq = (idx - m * 192) * 4;
    const int b = m >> 10, i = (m >> 5) & 31, j = m & 31;
    const int c = kq >> 8, rem = kq & 255, y = rem >> 4, x = rem & 15;
    const float4 v = *(const float4*)(img + ((size_t)((b * 3 + c) * 512 + i * 16 + y)) * 512 + j * 16 + x);
    ushort4 H, Lo;
    split2(v.x, H.x, Lo.x); split2(v.y, H.y, Lo.y);
    split2(v.z, H.z, Lo.z); split2(v.w, H.w, Lo.w);
    *(ushort4*)(a1h + (size_t)idx * 4) = H;
    *(ushort4*)(a1l + (size_t)idx * 4) = Lo;
}

// ---------------- prep: generic fp32 -> bf16 hi/lo ----------------
__global__ void k_split4(const float* __restrict__ src, u16* __restrict__ h, u16* __restrict__ l, int n4) {
    const int idx = blockIdx.x * 256 + threadIdx.x;
    if (idx >= n4) return;
    const float4 v = *(const float4*)(src + (size_t)idx * 4);
    ushort4 H, Lo;
    split2(v.x, H.x, Lo.x); split2(v.y, H.y, Lo.y);
    split2(v.z, H.z, Lo.z); split2(v.w, H.w, Lo.w);
    *(ushort4*)(h + (size_t)idx * 4) = H;
    *(ushort4*)(l + (size_t)idx * 4) = Lo;
}

// ---------------- prep: rpn weights (512,1024,3,3) -> B2[oc][d*1024+ic] bf16 hi/lo ----------------
__global__ void k_prep_w2(const float* __restrict__ w, u16* __restrict__ bh, u16* __restrict__ bl) {
    const int idx = blockIdx.x * 256 + threadIdx.x;        // 1,179,648
    const int oc = idx / 2304, r = idx - oc * 2304, d = r >> 8, ic4 = (r & 255) * 4;
    const float* p = w + (size_t)oc * 9216 + (size_t)ic4 * 9 + d;
    float4 v; v.x = p[0]; v.y = p[9]; v.z = p[18]; v.w = p[27];
    ushort4 H, Lo;
    split2(v.x, H.x, Lo.x); split2(v.y, H.y, Lo.y);
    split2(v.z, H.z, Lo.z); split2(v.w, H.w, Lo.w);
    const size_t o = (size_t)oc * 9216 + d * 1024 + ic4;
    *(ushort4*)(bh + o) = H;
    *(ushort4*)(bl + o) = Lo;
}

// ---------------- MFMA bf16x3 GEMM (conv1 / rpn) ----------------
// Block tile 128(M) x 64(N), 256 thr = 4 waves, wave tile 64x32, K-chunk 32.
// MODE 0: A linear rows; also writes bf16 hi/lo split of C when outH!=null.
// MODE 1: rpn gather from fm (bf16 h/l [2048][1024]); split-K via blockIdx.z.
template<int MODE>
__global__ __launch_bounds__(256, 1) void k_gemm(
        const u16* __restrict__ Agh, const u16* __restrict__ Agl,
        const u16* __restrict__ Bgh, const u16* __restrict__ Bgl,
        const float* __restrict__ bias, float* __restrict__ Cout,
        const int KA, const int KB, const int nchunk, const int ldc, const int do_bias_relu,
        u16* __restrict__ outH, u16* __restrict__ outL) {
    __shared__ __align__(16) u16 AsH[128 * 32];
    __shared__ __align__(16) u16 AsL[128 * 32];
    __shared__ __align__(16) u16 BsH[64 * 32];
    __shared__ __align__(16) u16 BsL[64 * 32];
    const int tid = threadIdx.x;
    const int w = tid >> 6, L = tid & 63;
    const int q = L >> 4, lr = L & 15;
    const int wm = w >> 1, wn = w & 1;
    const int m0 = blockIdx.x * 128, n0 = blockIdx.y * 64;
    const int icoff = blockIdx.z * 512;
    float* C = Cout + (MODE == 1 ? (size_t)blockIdx.z * (2048u * 512u) : (size_t)0);
    const int seg = L & 3, rsub = L >> 2;

    u16* ldst[6];
    const u16* gbase[6];
    int arow_b[6], arow_i[6], arow_j[6];
    int kindv[6];
#pragma unroll
    for (int s = 0; s < 6; ++s) {
        const int idx = w * 6 + s;
        int kind, inst;
        if (idx < 8)       { kind = 0; inst = idx; }
        else if (idx < 16) { kind = 1; inst = idx - 8; }
        else if (idx < 20) { kind = 2; inst = idx - 16; }
        else               { kind = 3; inst = idx - 20; }
        kindv[s] = kind;
        const int r = inst * 16 + rsub;
        u16* lb = (kind == 0) ? AsH : (kind == 1) ? AsL : (kind == 2) ? BsH : BsL;
        ldst[s] = lb + r * 32 + seg * 8;
        arow_b[s] = 0; arow_i[s] = 0; arow_j[s] = 0;
        if (kind >= 2) {
            const u16* gb = (kind == 2) ? Bgh : Bgl;
            gbase[s] = gb + (size_t)(n0 + r) * KB + seg * 8;
        } else if (MODE == 0) {
            const u16* gb = (kind == 0) ? Agh : Agl;
            gbase[s] = gb + (size_t)(m0 + r) * KA + seg * 8;
        } else {
            const int m = m0 + r;
            arow_b[s] = m >> 10; arow_i[s] = (m >> 5) & 31; arow_j[s] = m & 31;
            gbase[s] = (kind == 0) ? Agh : Agl;
        }
    }

    v4f acc[4][2];
#pragma unroll
    for (int t = 0; t < 4; ++t)
#pragma unroll
        for (int u2 = 0; u2 < 2; ++u2) acc[t][u2] = (v4f){0.f, 0.f, 0.f, 0.f};

    uint4 ubuf[6];
    bool okbuf[6];

#define LOAD6(c_) do { \
    int d_, ic_, kB_; \
    if (MODE == 0) { kB_ = (c_) * 32; d_ = 0; ic_ = kB_; } \
    else { d_ = (c_) >> 4; ic_ = icoff + ((c_) & 15) * 32; kB_ = d_ * 1024 + ic_; } \
    const int di_ = d_ / 3, dj_ = d_ - di_ * 3; \
    _Pragma("unroll") \
    for (int s = 0; s < 6; ++s) { \
        if (kindv[s] >= 2) { ubuf[s] = *(const uint4*)(gbase[s] + kB_); okbuf[s] = true; } \
        else if (MODE == 0) { ubuf[s] = *(const uint4*)(gbase[s] + ic_); okbuf[s] = true; } \
        else { \
            const int y_ = arow_i[s] + di_ - 1, x_ = arow_j[s] + dj_ - 1; \
            const bool ok_ = ((unsigned)y_ < 32u) && ((unsigned)x_ < 32u); \
            const int yc_ = ok_ ? y_ : 0, xc_ = ok_ ? x_ : 0; \
            ubuf[s] = *(const uint4*)(gbase[s] + (size_t)(((arow_b[s] * 32 + yc_) * 32 + xc_)) * 1024 + ic_ + seg * 8); \
            okbuf[s] = ok_; \
        } \
    } \
} while (0)

    LOAD6(0);
    for (int c = 0; c < nchunk; ++c) {
        __syncthreads();
#pragma unroll
        for (int s = 0; s < 6; ++s) {
            uint4 v = ubuf[s];
            if (MODE == 1 && !okbuf[s]) { v.x = 0u; v.y = 0u; v.z = 0u; v.w = 0u; }
            *(uint4*)ldst[s] = v;
        }
        __syncthreads();
        if (c + 1 < nchunk) LOAD6(c + 1);
        short8 ah[4], al[4], bh[2], bl[2];
#pragma unroll
        for (int t = 0; t < 4; ++t) {
            ah[t] = *(const short8*)(AsH + (wm * 64 + t * 16 + lr) * 32 + q * 8);
            al[t] = *(const short8*)(AsL + (wm * 64 + t * 16 + lr) * 32 + q * 8);
        }
#pragma unroll
        for (int u2 = 0; u2 < 2; ++u2) {
            bh[u2] = *(const short8*)(BsH + (wn * 32 + u2 * 16 + lr) * 32 + q * 8);
            bl[u2] = *(const short8*)(BsL + (wn * 32 + u2 * 16 + lr) * 32 + q * 8);
        }
#pragma unroll
        for (int t = 0; t < 4; ++t)
#pragma unroll
            for (int u2 = 0; u2 < 2; ++u2) {
                acc[t][u2] = __builtin_amdgcn_mfma_f32_16x16x32_bf16(ah[t], bh[u2], acc[t][u2], 0, 0, 0);
                acc[t][u2] = __builtin_amdgcn_mfma_f32_16x16x32_bf16(ah[t], bl[u2], acc[t][u2], 0, 0, 0);
                acc[t][u2] = __builtin_amdgcn_mfma_f32_16x16x32_bf16(al[t], bh[u2], acc[t][u2], 0, 0, 0);
            }
    }
#undef LOAD6

#pragma unroll
    for (int t = 0; t < 4; ++t) {
        const int row = m0 + wm * 64 + t * 16 + q * 4;
#pragma unroll
        for (int u2 = 0; u2 < 2; ++u2) {
            const int col = n0 + wn * 32 + u2 * 16 + lr;
            const float bv = do_bias_relu ? bias[col] : 0.f;
#pragma unroll
            for (int r = 0; r < 4; ++r) {
                float vv = acc[t][u2][r];
                if (do_bias_relu) vv = relu_(vv + bv);
                C[(size_t)(row + r) * ldc + col] = vv;
                if (MODE == 0 && outH != nullptr) {
                    u16 hh, ll; split2(vv, hh, ll);
                    outH[(size_t)(row + r) * 1024 + col] = hh;
                    outL[(size_t)(row + r) * 1024 + col] = ll;
                }
            }
        }
    }
}

// ---------------- rpn heads (1x1 convs) + split-K reduce + anchors + proposals ----------------
__global__ __launch_bounds__(64) void k_rpn_heads(const float* __restrict__ part,
        const float* __restrict__ rpnb,
        const float* __restrict__ regw, const float* __restrict__ regb,
        const float* __restrict__ clsw, const float* __restrict__ clsb,
        float* __restrict__ out, float* __restrict__ prop, float* __restrict__ scr) {
    __shared__ __align__(16) float hrow[512];
    const int m = blockIdx.x, tid = threadIdx.x;
    const int b = m >> 10, qd = m & 1023, ii = qd >> 5, jj = qd & 31;
    for (int i = tid * 4; i < 512; i += 256) {
        const float4 p0 = *(const float4*)(part + (size_t)m * 512 + i);
        const float4 p1 = *(const float4*)(part + (size_t)(2048 * 512) + (size_t)m * 512 + i);
        const float4 bb = *(const float4*)(rpnb + i);
        float4 o;
        o.x = relu_(p0.x + p1.x + bb.x); o.y = relu_(p0.y + p1.y + bb.y);
        o.z = relu_(p0.z + p1.z + bb.z); o.w = relu_(p0.w + p1.w + bb.w);
        *(float4*)&hrow[i] = o;
    }
    __syncthreads();
    if (tid < 45) {
        const int isreg = (tid < 36);
        const float* wp = isreg ? (regw + (size_t)tid * 512) : (clsw + (size_t)(tid - 36) * 512);
        float acc2 = isreg ? regb[tid] : clsb[tid - 36];
        for (int k = 0; k < 512; k += 4) {
            const float4 wv = *(const float4*)(wp + k);
            acc2 += hrow[k + 0] * wv.x; acc2 += hrow[k + 1] * wv.y;
            acc2 += hrow[k + 2] * wv.z; acc2 += hrow[k + 3] * wv.w;
        }
        if (isreg) {
            out[O_RPN_REG + (size_t)b * 36864 + qd * 36 + tid] = acc2;
            const int a = tid >> 2, cc = tid & 3;
            float w2, h2; anchor_wh(a, w2, h2);
            const float cx = ((float)jj + 0.5f) * 16.f, cy = ((float)ii + 0.5f) * 16.f;
            const float av = (cc == 0) ? cx - w2 : (cc == 1) ? cy - h2 : (cc == 2) ? cx + w2 : cy + h2;
            prop[(size_t)b * 36864 + qd * 36 + tid] = acc2 + av;
        } else {
            const int n = tid - 36;
            out[O_RPN_CLS + (size_t)b * 9216 + qd * 9 + n] = acc2;
            scr[(size_t)b * 9216 + qd * 9 + n] = acc2;
        }
    }
    if (b == 0 && tid >= 48 && tid < 57) {
        const int a = tid - 48;
        float w2, h2; anchor_wh(a, w2, h2);
        const float cx = ((float)jj + 0.5f) * 16.f, cy = ((float)ii + 0.5f) * 16.f;
        const float4 av4 = make_float4(cx - w2, cy - h2, cx + w2, cy + h2);
        *(float4*)(out + O_ANCH + (size_t)(qd * 9 + a) * 4) = av4;
    }
}

// ---------------- NMS v3: 512 thr, 18 cand/thread, ALL static register indexing ----------------
// bx/sv stay in VGPRs (every k-loop fully unrolled, no dynamic subscripts -> no scratch).
// One barrier per iteration (ping-pong wave-result slots); selected box re-read from
// global prop (same address in all lanes -> single broadcast L2 transaction).
__global__ __launch_bounds__(512) void k_nms3(const float* __restrict__ prop,
        const float* __restrict__ scr, float* __restrict__ out) {
    __shared__ float wv_[2][8];
    __shared__ int wi_[2][8];
    const int b = blockIdx.x, tid = threadIdx.x;
    const int lane = tid & 63, wid = tid >> 6;
    const float* P = prop + (size_t)b * 36864;
    float4 bx[18]; float sv[18];
#pragma unroll
    for (int k = 0; k < 18; ++k) {
        const int i = tid * 18 + k;
        bx[k] = *(const float4*)(P + (size_t)i * 4);
        sv[k] = scr[b * 9216 + i];
    }
    for (int t = 0; t < 20; ++t) {
        float bv = -3.4e38f; int bi = 0;
#pragma unroll
        for (int k = 0; k < 18; ++k)
            if (sv[k] > bv) { bv = sv[k]; bi = tid * 18 + k; }   // ascending idx -> first max kept
#pragma unroll
        for (int off = 1; off < 64; off <<= 1) {
            const float ov = __shfl_xor(bv, off);
            const int oi = __shfl_xor(bi, off);
            if (ov > bv || (ov == bv && oi < bi)) { bv = ov; bi = oi; }
        }
        if (lane == 0) { wv_[t & 1][wid] = bv; wi_[t & 1][wid] = bi; }
        __syncthreads();
        float rb = wv_[t & 1][0]; int sel = wi_[t & 1][0];
#pragma unroll
        for (int j = 1; j < 8; ++j) {
            const float v2 = wv_[t & 1][j]; const int i2 = wi_[t & 1][j];
            if (v2 > rb || (v2 == rb && i2 < sel)) { rb = v2; sel = i2; }
        }
        const float4 bb = *(const float4*)(P + (size_t)sel * 4);   // broadcast read
        if (tid == 0) {
            *(float4*)(out + O_NMS_REG + (size_t)(b * 20 + t) * 4) = bb;
            out[O_NMS_CLS + b * 20 + t] = rb;
        }
        const float ab2 = fmaxf(bb.z - bb.x, 0.f) * fmaxf(bb.w - bb.y, 0.f);
#pragma unroll
        for (int k = 0; k < 18; ++k) {
            const float ix1 = fmaxf(bb.x, bx[k].x), iy1 = fmaxf(bb.y, bx[k].y);
            const float ix2 = fminf(bb.z, bx[k].z), iy2 = fminf(bb.w, bx[k].w);
            const float inter = fmaxf(ix2 - ix1, 0.f) * fmaxf(iy2 - iy1, 0.f);
            const float ar2 = fmaxf(bx[k].z - bx[k].x, 0.f) * fmaxf(bx[k].w - bx[k].y, 0.f);
            const float iou = inter / (ab2 + ar2 - inter + 1e-8f);
            if (iou > 0.3f || (tid * 18 + k) == sel) sv[k] = NEGV;
        }
    }
}

// ---------------- ROI align -> flat [40][50176], col = c*49 + py*7 + px ----------------
__global__ __launch_bounds__(256) void k_roi(const float* __restrict__ fm,
        const int* __restrict__ img_id, const float* __restrict__ nreg,
        float* __restrict__ flat) {
    const int py = blockIdx.x, roi = blockIdx.y, b = blockIdx.z;
    const float* bx = nreg + (size_t)(b * 20 + roi) * 4;
    const float b0 = bx[0] * 0.0625f, b1 = bx[1] * 0.0625f;
    const float b2 = bx[2] * 0.0625f, b3 = bx[3] * 0.0625f;
    const float wd = fmaxf(b2 - b0, 0.f), hg = fmaxf(b3 - b1, 0.f);
    const float tyv = ((float)py + 0.5f) / 7.0f;
    const float ycv = fminf(fmaxf(b1 + hg * tyv, 0.f), 31.f);
    const float y0f = floorf(ycv);
    const int y0 = (int)y0f, y1 = min(y0 + 1, 31);
    const float ly = ycv - y0f, omly = 1.f - ly;
    const int bb = img_id[b];
    const float* fmb = fm + (size_t)bb * (32 * 32 * 1024);
    const size_t orow = (size_t)(b * 20 + roi) * 50176 + (size_t)py * 7;
    for (int px = 0; px < 7; ++px) {
        const float txv = ((float)px + 0.5f) / 7.0f;
        const float xcv = fminf(fmaxf(b0 + wd * txv, 0.f), 31.f);
        const float x0f = floorf(xcv);
        const int x0 = (int)x0f, x1 = min(x0 + 1, 31);
        const float lx = xcv - x0f, omlx = 1.f - lx;
        const int o00 = ((y0 * 32) + x0) << 10, o01 = ((y0 * 32) + x1) << 10;
        const int o10 = ((y1 * 32) + x0) << 10, o11 = ((y1 * 32) + x1) << 10;
        for (int u = 0; u < 4; ++u) {
            const int c = threadIdx.x + u * 256;
            const float v00 = fmb[o00 + c], v01 = fmb[o01 + c];
            const float v10 = fmb[o10 + c], v11 = fmb[o11 + c];
            const float val = ((v00 * omly) * omlx) + ((v01 * omly) * lx)
                            + ((v10 * ly) * omlx) + ((v11 * ly) * lx);
            flat[orow + (size_t)c * 49 + px] = val;
        }
    }
}

// ---------------- hf accumulator init (bias) ----------------
__global__ void k_hf_init(const float* __restrict__ fcb, float* __restrict__ hf) {
    const int i = blockIdx.x * 256 + threadIdx.x;
    if (i < 40 * 1024) hf[i] = fcb[i & 1023];
}

// ---------------- FC GEMM MFMA bf16x3: 40(pad48) x 1024 x 50176 ----------------
__global__ __launch_bounds__(256, 2) void k_fc_mfma(const float* __restrict__ flat,
        const float* __restrict__ fcw, float* __restrict__ hf) {
    __shared__ __align__(16) u16 AsH[4 * 48 * 8];
    __shared__ __align__(16) u16 AsL[4 * 48 * 8];
    __shared__ __align__(16) u16 BsH[4 * 256 * 8];
    __shared__ __align__(16) u16 BsL[4 * 256 * 8];
    const int tid = threadIdx.x;
    const int w = tid >> 6, L = tid & 63, q = L >> 4, lr = L & 15;
    const int n0 = blockIdx.x * 256, kb = blockIdx.y * 512;
    if (tid < 32) {
        const int oct = tid >> 3, m = 40 + (tid & 7);
        *(uint4*)(AsH + (oct * 48 + m) * 8) = make_uint4(0, 0, 0, 0);
        *(uint4*)(AsL + (oct * 48 + m) * 8) = make_uint4(0, 0, 0, 0);
    }
    const int am = tid >> 2, aoct = tid & 3;
    const float* abase = flat + (size_t)am * 50176 + kb + aoct * 8;
    const float* bcol = fcw + n0 + tid;

    v4f acc[3][4];
#pragma unroll
    for (int mt = 0; mt < 3; ++mt)
#pragma unroll
        for (int nt = 0; nt < 4; ++nt) acc[mt][nt] = (v4f){0.f, 0.f, 0.f, 0.f};

    float areg[8];
    float breg[4][8];

#define LOADF(c_) do { \
    if (tid < 160) { \
        const float4 u_ = *(const float4*)(abase + (c_) * 32); \
        const float4 v_ = *(const float4*)(abase + (c_) * 32 + 4); \
        areg[0] = u_.x; areg[1] = u_.y; areg[2] = u_.z; areg[3] = u_.w; \
        areg[4] = v_.x; areg[5] = v_.y; areg[6] = v_.z; areg[7] = v_.w; \
    } \
    _Pragma("unroll") \
    for (int o_ = 0; o_ < 4; ++o_) \
        _Pragma("unroll") \
        for (int j_ = 0; j_ < 8; ++j_) \
            breg[o_][j_] = bcol[(size_t)(kb + (c_) * 32 + o_ * 8 + j_) * 1024]; \
} while (0)

    LOADF(0);
    for (int c = 0; c < 16; ++c) {
        __syncthreads();
        if (tid < 160)
            split8_store(areg, AsH + (aoct * 48 + am) * 8, AsL + (aoct * 48 + am) * 8);
#pragma unroll
        for (int o = 0; o < 4; ++o)
            split8_store(breg[o], BsH + (o * 256 + tid) * 8, BsL + (o * 256 + tid) * 8);
        __syncthreads();
        if (c + 1 < 16) LOADF(c + 1);
        short8 ah[3], al[3], bh2[4], bl2[4];
#pragma unroll
        for (int mt = 0; mt < 3; ++mt) {
            ah[mt] = *(const short8*)(AsH + (q * 48 + mt * 16 + lr) * 8);
            al[mt] = *(const short8*)(AsL + (q * 48 + mt * 16 + lr) * 8);
        }
#pragma unroll
        for (int nt = 0; nt < 4; ++nt) {
            bh2[nt] = *(const short8*)(BsH + (q * 256 + w * 64 + nt * 16 + lr) * 8);
            bl2[nt] = *(const short8*)(BsL + (q * 256 + w * 64 + nt * 16 + lr) * 8);
        }
#pragma unroll
        for (int mt = 0; mt < 3; ++mt)
#pragma unroll
            for (int nt = 0; nt < 4; ++nt) {
                acc[mt][nt] = __builtin_amdgcn_mfma_f32_16x16x32_bf16(ah[mt], bh2[nt], acc[mt][nt], 0, 0, 0);
                acc[mt][nt] = __builtin_amdgcn_mfma_f32_16x16x32_bf16(ah[mt], bl2[nt], acc[mt][nt], 0, 0, 0);
                acc[mt][nt] = __builtin_amdgcn_mfma_f32_16x16x32_bf16(al[mt], bh2[nt], acc[mt][nt], 0, 0, 0);
            }
    }
#undef LOADF

#pragma unroll
    for (int mt = 0; mt < 3; ++mt) {
#pragma unroll
        for (int nt = 0; nt < 4; ++nt) {
#pragma unroll
            for (int r = 0; r < 4; ++r) {
                const int row = mt * 16 + q * 4 + r;
                if (row < 40)
                    atomicAdd(hf + (size_t)row * 1024 + n0 + w * 64 + nt * 16 + lr, acc[mt][nt][r]);
            }
        }
    }
}

// ---------------- final heads ----------------
__global__ __launch_bounds__(64) void k_heads(const float* __restrict__ hf,
        const float* __restrict__ regw, const float* __restrict__ regb,
        const float* __restrict__ clsw, const float* __restrict__ clsb,
        float* __restrict__ out) {
    __shared__ __align__(16) float hrow[1024];
    const int m = blockIdx.x, tid = threadIdx.x;
    for (int i = tid * 4; i < 1024; i += 256) {
        const float4 v = *(const float4*)(hf + (size_t)m * 1024 + i);
        hrow[i + 0] = relu_(v.x); hrow[i + 1] = relu_(v.y);
        hrow[i + 2] = relu_(v.z); hrow[i + 3] = relu_(v.w);
    }
    __syncthreads();
    if (tid < 25) {
        float acc2 = 0.f;
        if (tid < 4) {
            for (int k = 0; k < 1024; ++k) acc2 += hrow[k] * regw[(size_t)k * 4 + tid];
            out[O_RCNN_REG + m * 4 + tid] = acc2 + regb[tid];
        } else {
            const int n = tid - 4;
            for (int k = 0; k < 1024; ++k) acc2 += hrow[k] * clsw[(size_t)k * 21 + n];
            out[O_RCNN_CLS + m * 21 + n] = acc2 + clsb[n];
        }
    }
}

extern "C" void kernel_launch(void* const* d_in, const int* in_sizes, int n_in,
                              void* d_out, int out_size, void* d_ws, size_t ws_size,
                              hipStream_t stream) {
    (void)in_sizes; (void)n_in; (void)out_size; (void)ws_size;
    const float* img       = (const float*)d_in[0];
    const int*   img_id    = (const int*)  d_in[1];
    const float* cnn_w     = (const float*)d_in[2];
    const float* cnn_b     = (const float*)d_in[3];
    const float* rpn_w     = (const float*)d_in[4];
    const float* rpn_b     = (const float*)d_in[5];
    const float* rpn_reg_w = (const float*)d_in[6];
    const float* rpn_reg_b = (const float*)d_in[7];
    const float* rpn_cls_w = (const float*)d_in[8];
    const float* rpn_cls_b = (const float*)d_in[9];
    const float* fc_w      = (const float*)d_in[10];
    const float* fc_b      = (const float*)d_in[11];
    const float* reg_w     = (const float*)d_in[12];
    const float* reg_b     = (const float*)d_in[13];
    const float* cls_w     = (const float*)d_in[14];
    const float* cls_b     = (const float*)d_in[15];
    float* out = (float*)d_out;
    float* ws  = (float*)d_ws;

    float* fm   = ws + W_FM;
    float* prop = ws + W_PROP;
    float* scr  = ws + W_SCR;
    float* flat = ws + W_FLAT;
    float* hf   = ws + W_HF;
    u16* a1h = (u16*)(ws + W_A1H);
    u16* a1l = (u16*)(ws + W_A1L);
    u16* b1h = (u16*)(ws + W_B1H);
    u16* b1l = (u16*)(ws + W_B1L);
    u16* fmh = (u16*)(ws + W_FMH);
    u16* fml = (u16*)(ws + W_FML);
    u16* b2h = (u16*)(ws + W_B2H);
    u16* b2l = (u16*)(ws + W_B2L);
    float* part = ws + W_PART;

    // conv1 path (epilogue also writes fmh/fml bf16 split)
    k_prep_a1<<<1536, 256, 0, stream>>>(img, a1h, a1l);
    k_split4<<<768, 256, 0, stream>>>(cnn_w, b1h, b1l, 196608);
    k_prep_w2<<<4608, 256, 0, stream>>>(rpn_w, b2h, b2l);
    k_gemm<0><<<dim3(16, 16, 1), 256, 0, stream>>>(a1h, a1l, b1h, b1l, cnn_b, fm,
                                                   768, 768, 24, 1024, 1, fmh, fml);
    // rpn path
    k_gemm<1><<<dim3(16, 8, 2), 256, 0, stream>>>(fmh, fml, b2h, b2l, nullptr, part,
                                                  1024, 9216, 144, 512, 0, nullptr, nullptr);
    k_rpn_heads<<<2048, 64, 0, stream>>>(part, rpn_b, rpn_reg_w, rpn_reg_b, rpn_cls_w, rpn_cls_b,
                                         out, prop, scr);
    k_nms3<<<2, 512, 0, stream>>>(prop, scr, out);
    k_roi<<<dim3(7, 20, 2), 256, 0, stream>>>(fm, img_id, out + O_NMS_REG, flat);
    k_hf_init<<<160, 256, 0, stream>>>(fc_b, hf);
    k_fc_mfma<<<dim3(4, 98), 256, 0, stream>>>(flat, fc_w, hf);
    k_heads<<<40, 64, 0, stream>>>(hf, reg_w, reg_b, cls_w, cls_b, out);
}